// Round 5
// baseline (918.296 us; speedup 1.0000x reference)
//
#include <hip/hip_runtime.h>
#include <stdint.h>

namespace {

constexpr int B_ = 2, T_ = 2048, C_ = 2048, H_ = 16, D_ = 128;
constexpr int R_ = B_ * T_;                 // 4096 token rows (b*T + t)
constexpr float EPSF = 1e-5f;
constexpr float INV_SQRT_D = 0.08838834764831845f;   // 1/sqrt(128)
constexpr float LOG2E = 1.4426950408889634f;
constexpr float LOG2_127 = 6.988684686772166f;

// ---- workspace layout (bytes) ----
constexpr size_t OFF_WSUM = 0;                                   // double[4]
constexpr size_t OFF_SW   = 64;                                  // float[4]
constexpr size_t OFF_WT   = 256;                                 // int8[4][C*C] ternary
constexpr size_t OFF_XQ   = OFF_WT   + (size_t)4 * C_ * C_;      // int8[R*C]
constexpr size_t OFF_SX   = OFF_XQ   + (size_t)R_ * C_;          // float[R]
constexpr size_t OFF_QKV  = OFF_SX   + (size_t)R_ * 4;           // int8[3][B*H*T*D]
constexpr size_t OFF_SQKV = OFF_QKV  + (size_t)3 * R_ * C_;      // float[3][B*H*T]
constexpr size_t OFF_YQ   = OFF_SQKV + (size_t)3 * R_ * H_ * 4;  // int8[R*C]
constexpr size_t OFF_SY   = OFF_YQ   + (size_t)R_ * C_;          // float[R*H]
constexpr size_t OFF_OUTP = OFF_SY   + (size_t)R_ * H_ * 4;      // float[R*C]
// vhiT/vloT (bf16 [bh][d][t], 16.78 MB each) alias OUTP (33.55 MB): dead before
// outproj writes outp (stream-ordered), so no extra workspace.
constexpr size_t OFF_VHI  = OFF_OUTP;
constexpr size_t VT_ELEMS = (size_t)B_ * H_ * D_ * T_;

typedef int   i32x4 __attribute__((ext_vector_type(4)));
typedef short s16x8 __attribute__((ext_vector_type(8)));
typedef float f32x4 __attribute__((ext_vector_type(4)));

__device__ __forceinline__ i32x4 mfma_i8(i32x4 a, i32x4 b, i32x4 c) {
  return __builtin_amdgcn_mfma_i32_16x16x64_i8(a, b, c, 0, 0, 0);
}
__device__ __forceinline__ f32x4 mfma_bf16(s16x8 a, s16x8 b, f32x4 c) {
  return __builtin_amdgcn_mfma_f32_16x16x32_bf16(a, b, c, 0, 0, 0);
}

#if __has_builtin(__builtin_amdgcn_exp2f)
__device__ __forceinline__ float fast_exp2(float x) { return __builtin_amdgcn_exp2f(x); }
#else
__device__ __forceinline__ float fast_exp2(float x) { return exp2f(x); }
#endif

// RTNE float->bf16 bits (matches numpy RTNE)
__device__ __forceinline__ short f2bf(float f) {
  union { float f; uint32_t u; } v; v.f = f;
  uint32_t r = v.u + 0x7fffu + ((v.u >> 16) & 1u);
  return (short)(r >> 16);
}
__device__ __forceinline__ float bf2f(short h) {
  union { uint32_t u; float f; } v; v.u = ((uint32_t)(uint16_t)h) << 16;
  return v.f;
}

// ---------------- mean(|W|) for the 4 weight matrices (double accum) ----------------
__global__ __launch_bounds__(256) void wabs_sum_kernel(
    const float* __restrict__ W0, const float* __restrict__ W1,
    const float* __restrict__ W2, const float* __restrict__ W3,
    double* __restrict__ wsum)
{
  const int w   = blockIdx.x >> 6;
  const int blk = blockIdx.x & 63;
  const float* W = (w == 0) ? W0 : (w == 1) ? W1 : (w == 2) ? W2 : W3;
  const int n = C_ * C_;
  double s = 0.0;
  for (int i = blk * 256 + (int)threadIdx.x; i < n; i += 64 * 256)
    s += (double)fabsf(W[i]);
  __shared__ double sm[256];
  sm[threadIdx.x] = s;
  __syncthreads();
  for (int o = 128; o > 0; o >>= 1) {
    if ((int)threadIdx.x < o) sm[threadIdx.x] += sm[threadIdx.x + o];
    __syncthreads();
  }
  if (threadIdx.x == 0) atomicAdd(&wsum[w], sm[0]);
}

// ---------------- ternary weight quant ----------------
__global__ __launch_bounds__(256) void wquant_kernel(
    const float* __restrict__ W0, const float* __restrict__ W1,
    const float* __restrict__ W2, const float* __restrict__ W3,
    const double* __restrict__ wsum, int8_t* __restrict__ Wt, float* __restrict__ sw)
{
  const int w = blockIdx.x >> 10;
  const float* W = (w == 0) ? W0 : (w == 1) ? W1 : (w == 2) ? W2 : W3;
  const int n = C_ * C_;
  const float s = fmaxf((float)(wsum[w] * (1.0 / (double)n)), EPSF);
  int8_t* dst = Wt + (size_t)w * n;
  const int base = (blockIdx.x & 1023) * 256 + (int)threadIdx.x;
  for (int i = base; i < n; i += 1024 * 256) {
    float t = rintf(W[i] / s);
    t = fminf(fmaxf(t, -1.f), 1.f);
    dst[i] = (int8_t)t;
  }
  if (base == 0) sw[w] = s;
}

// ---------------- per-token act_quant of x ----------------
__global__ __launch_bounds__(256) void xquant_kernel(
    const float* __restrict__ x, int8_t* __restrict__ xq, float* __restrict__ sx)
{
  const int r = blockIdx.x;
  const float* xr = x + (size_t)r * C_;
  float am = 0.f;
  for (int j = threadIdx.x; j < C_; j += 256) am = fmaxf(am, fabsf(xr[j]));
  __shared__ float sm[256];
  sm[threadIdx.x] = am;
  __syncthreads();
  for (int o = 128; o > 0; o >>= 1) {
    if ((int)threadIdx.x < o) sm[threadIdx.x] = fmaxf(sm[threadIdx.x], sm[threadIdx.x + o]);
    __syncthreads();
  }
  const float m = fmaxf(sm[0], EPSF);
  const float scale = 127.f / m;
  for (int j = threadIdx.x; j < C_; j += 256) {
    float q = fminf(fmaxf(rintf(xr[j] * scale), -128.f), 127.f);
    xq[(size_t)r * C_ + j] = (int8_t)q;
  }
  if (threadIdx.x == 0) sx[r] = m / 127.f;
}

// ---------------- q/k/v projection: i8 MFMA, LDS-staged (R2-proven) ----------------
// grid (16 heads, R/128, 3). Block tile 128x128 (one head), wave 64x64 = 4x4 tiles.
__global__ __launch_bounds__(256) void proj_mfma_kernel(
    const int8_t* __restrict__ xq, const float* __restrict__ sx,
    const int8_t* __restrict__ Wt, const float* __restrict__ sw4,
    int8_t* __restrict__ qkv, float* __restrict__ sqkv)
{
  const int h    = blockIdx.x;
  const int r0   = blockIdx.y * 128;
  const int wsel = blockIdx.z;
  const int tid  = (int)threadIdx.x;
  const int wv   = tid >> 6;
  const int lane = tid & 63;
  const int quad = lane >> 4;
  const int l15  = lane & 15;
  const int rh   = wv >> 1, ch = wv & 1;
  const int8_t* Wm = Wt + (size_t)wsel * C_ * C_;

  __shared__ __align__(16) char As[128 * 80];   // [row][64B data + 16 pad]
  __shared__ __align__(16) char Bs[128 * 80];   // [outcol][64B data + 16 pad]
  __shared__ int rmaxs[128];
  if (tid < 128) rmaxs[tid] = 0;

  i32x4 acc[4][4];
  #pragma unroll
  for (int i = 0; i < 4; ++i)
    #pragma unroll
    for (int j = 0; j < 4; ++j) acc[i][j] = i32x4{0, 0, 0, 0};

  for (int k0 = 0; k0 < C_; k0 += 64) {
    #pragma unroll
    for (int it = 0; it < 2; ++it) {
      int idx = tid + it * 256;          // 512: row = idx>>2, seg = idx&3
      int row = idx >> 2, seg = idx & 3;
      *(uint4*)(As + row * 80 + seg * 16) =
          *(const uint4*)(xq + (size_t)(r0 + row) * C_ + k0 + seg * 16);
      *(uint4*)(Bs + row * 80 + seg * 16) =
          *(const uint4*)(Wm + (size_t)(h * 128 + row) * C_ + k0 + seg * 16);
    }
    __syncthreads();
    i32x4 a[4], b[4];
    #pragma unroll
    for (int rt = 0; rt < 4; ++rt)
      a[rt] = *(const i32x4*)(As + (rh * 64 + rt * 16 + l15) * 80 + quad * 16);
    #pragma unroll
    for (int ct = 0; ct < 4; ++ct)
      b[ct] = *(const i32x4*)(Bs + (ch * 64 + ct * 16 + l15) * 80 + quad * 16);
    #pragma unroll
    for (int rt = 0; rt < 4; ++rt)
      #pragma unroll
      for (int ct = 0; ct < 4; ++ct)
        acc[rt][ct] = mfma_i8(a[rt], b[ct], acc[rt][ct]);
    __syncthreads();
  }

  // per-row abs-max over the full head via LDS atomicMax
  #pragma unroll
  for (int rt = 0; rt < 4; ++rt)
    #pragma unroll
    for (int r = 0; r < 4; ++r) {
      int m = 0;
      #pragma unroll
      for (int ct = 0; ct < 4; ++ct) {
        int v = acc[rt][ct][r];
        int av = v < 0 ? -v : v;
        m = m > av ? m : av;
      }
      #pragma unroll
      for (int mm = 1; mm < 16; mm <<= 1) {
        int o = __shfl_xor(m, mm, 64);
        m = m > o ? m : o;
      }
      if (l15 == 0) atomicMax(&rmaxs[rh * 64 + rt * 16 + quad * 4 + r], m);
    }
  __syncthreads();

  const float swv = sw4[wsel];
  #pragma unroll
  for (int rt = 0; rt < 4; ++rt)
    #pragma unroll
    for (int r = 0; r < 4; ++r) {
      const int rowl = rh * 64 + rt * 16 + quad * 4 + r;
      const int rglob = r0 + rowl;
      const int mN = rmaxs[rowl];
      const float qscale = (mN > 0) ? 127.f / (float)mN : 0.f;
      const int bb = rglob >> 11;
      const int tt = rglob & (T_ - 1);
      const size_t obase = ((size_t)(bb * H_ + h) * T_ + tt) * D_;
      #pragma unroll
      for (int ct = 0; ct < 4; ++ct) {
        const int col = ch * 64 + ct * 16 + l15;
        float q = rintf((float)acc[rt][ct][r] * qscale);
        q = fminf(fmaxf(q, -128.f), 127.f);
        qkv[(size_t)wsel * R_ * C_ + obase + col] = (int8_t)q;
      }
      if (ch == 0 && l15 == 0) {
        float maxq = (float)mN * sx[rglob] * swv;
        sqkv[(size_t)wsel * R_ * H_ + (size_t)(bb * H_ + h) * T_ + tt] =
            fmaxf(maxq, EPSF) / 127.f;
      }
    }
}

// ---------------- V dequant+transpose: int8 [bh][t][d] -> bf16 hi/lo [bh][d][t] ----------
__global__ __launch_bounds__(256) void vtrans_kernel(
    const int8_t* __restrict__ vq, const float* __restrict__ sv,
    short* __restrict__ vhiT, short* __restrict__ vloT)
{
  const int bh = blockIdx.y;
  const int s0 = blockIdx.x * 64;
  const int tid = (int)threadIdx.x;
  __shared__ __align__(16) int8_t Vs[64][144];
  __shared__ float svs[64];
  const int8_t* vbase = vq + ((size_t)bh * T_ + s0) * D_;
  #pragma unroll
  for (int it = 0; it < 2; ++it) {
    int idx = tid + it * 256;
    int row = idx >> 3, seg = idx & 7;
    *(uint4*)(&Vs[row][seg * 16]) = *(const uint4*)(vbase + row * 128 + seg * 16);
  }
  if (tid < 64) svs[tid] = sv[(size_t)bh * T_ + s0 + tid];
  __syncthreads();
  const int d = tid >> 1;
  const int kh = (tid & 1) * 32;
  uint32_t oh[16], ol[16];
  #pragma unroll
  for (int i = 0; i < 32; i += 2) {
    const int k0 = kh + i, k1 = kh + i + 1;
    float v0 = (float)(int)Vs[k0][d] * svs[k0];
    float v1 = (float)(int)Vs[k1][d] * svs[k1];
    short h0 = f2bf(v0), h1 = f2bf(v1);
    short l0 = f2bf(v0 - bf2f(h0)), l1 = f2bf(v1 - bf2f(h1));
    oh[i >> 1] = (uint32_t)(uint16_t)h0 | ((uint32_t)(uint16_t)h1 << 16);
    ol[i >> 1] = (uint32_t)(uint16_t)l0 | ((uint32_t)(uint16_t)l1 << 16);
  }
  const size_t dbase = ((size_t)bh * D_ + d) * T_ + s0 + kh;
  #pragma unroll
  for (int i = 0; i < 4; ++i) {
    uint4 a, b;
    a.x = oh[4 * i]; a.y = oh[4 * i + 1]; a.z = oh[4 * i + 2]; a.w = oh[4 * i + 3];
    b.x = ol[4 * i]; b.y = ol[4 * i + 1]; b.z = ol[4 * i + 2]; b.w = ol[4 * i + 3];
    *(uint4*)(vhiT + dbase + 8 * i) = a;
    *(uint4*)(vloT + dbase + 8 * i) = b;
  }
}

// ---------------- fused attention v5 -------------------------------------------------
// grid (B*H, T/128). 4 waves x 32 q-rows. K and sk read DIRECT from global in both
// passes (i8 fragment layout == row-major; L1/L2 serve the 4-wave reuse) -> pass 1 has
// ZERO barriers. LDS holds only V hi/lo tiles (2 barriers/chunk) + W round-trip
// (wave-private rows, fence only). 51 KB LDS -> 3 blocks/CU. All LDS rows stride 136 B
// (2-way bank aliasing = free). Softmax: wu = exp2(s*log2e + log2(127) - m*log2e);
// zacc accumulates 127Z; sv pre-folded into V (vtrans).
__global__ __launch_bounds__(256) void attn_mfma_kernel(
    const int8_t* __restrict__ qq, const int8_t* __restrict__ kq,
    const float* __restrict__ sq, const float* __restrict__ sk,
    const short* __restrict__ vhiT, const short* __restrict__ vloT,
    int8_t* __restrict__ yq, float* __restrict__ sy)
{
  const int bh  = blockIdx.x;
  const int t0  = blockIdx.y * 128;
  const int tid = (int)threadIdx.x;
  const int w    = tid >> 6;
  const int lane = tid & 63;
  const int quad = lane >> 4;
  const int l15  = lane & 15;

  __shared__ __align__(16) char smem[52224];
  char* Vh  = smem;            // [128 d][136] bf16 hi (64 keys)
  char* Vl  = smem + 17408;    // [128 d][136] bf16 lo
  char* Wsb = smem + 34816;    // [128 q][136] bf16 integer weights (64 keys)
  short* WsS = (short*)Wsb;    // stride 68 shorts

  const int qrow0 = t0 + 32 * w;

  // Q A-frags + per-row scale factors, direct from global (read once)
  i32x4 aq[2][2];
  #pragma unroll
  for (int qt = 0; qt < 2; ++qt)
    #pragma unroll
    for (int hf = 0; hf < 2; ++hf)
      aq[qt][hf] = *(const i32x4*)(qq + ((size_t)bh * T_ + qrow0 + qt * 16 + l15) * D_ + hf * 64 + quad * 16);

  float f0[2][4];
  #pragma unroll
  for (int qt = 0; qt < 2; ++qt)
    #pragma unroll
    for (int r = 0; r < 4; ++r)
      f0[qt][r] = sq[(size_t)bh * T_ + qrow0 + qt * 16 + quad * 4 + r] * INV_SQRT_D;

  // ---- pass 1: exact rowmax of c*skc -- K/sk direct from global, NO barriers ----
  float rmaxc[2][4];
  #pragma unroll
  for (int qt = 0; qt < 2; ++qt)
    #pragma unroll
    for (int r = 0; r < 4; ++r) rmaxc[qt][r] = -3e38f;

  for (int s0 = 0; s0 < T_; s0 += 64) {
    const int8_t* kb = kq + ((size_t)bh * T_ + s0) * D_;
    const float*  skb = sk + (size_t)bh * T_ + s0;
    #pragma unroll
    for (int kt = 0; kt < 4; ++kt) {
      const int key = kt * 16 + l15;
      i32x4 b0 = *(const i32x4*)(kb + (size_t)key * D_ + quad * 16);
      i32x4 b1 = *(const i32x4*)(kb + (size_t)key * D_ + 64 + quad * 16);
      const float skc = skb[key];
      #pragma unroll
      for (int qt = 0; qt < 2; ++qt) {
        i32x4 c = i32x4{0, 0, 0, 0};
        c = mfma_i8(aq[qt][0], b0, c);
        c = mfma_i8(aq[qt][1], b1, c);
        #pragma unroll
        for (int r = 0; r < 4; ++r)
          rmaxc[qt][r] = fmaxf(rmaxc[qt][r], (float)c[r] * skc);
      }
    }
  }
  #pragma unroll
  for (int mm = 1; mm < 16; mm <<= 1)
    #pragma unroll
    for (int qt = 0; qt < 2; ++qt)
      #pragma unroll
      for (int r = 0; r < 4; ++r)
        rmaxc[qt][r] = fmaxf(rmaxc[qt][r], __shfl_xor(rmaxc[qt][r], mm, 64));

  float f1[2][4], g[2][4];
  #pragma unroll
  for (int qt = 0; qt < 2; ++qt)
    #pragma unroll
    for (int r = 0; r < 4; ++r) {
      f1[qt][r] = f0[qt][r] * LOG2E;
      g[qt][r]  = LOG2_127 - (rmaxc[qt][r] * f0[qt][r]) * LOG2E;
    }

  // ---- pass 2: quantized softmax + PV ----
  float zacc[2][4] = {};
  f32x4 yacc[2][8];
  #pragma unroll
  for (int qt = 0; qt < 2; ++qt)
    #pragma unroll
    for (int dt = 0; dt < 8; ++dt) yacc[qt][dt] = f32x4{0.f, 0.f, 0.f, 0.f};

  for (int s0 = 0; s0 < T_; s0 += 64) {
    __syncthreads();   // WAR: prev chunk's V reads complete
    // V hi/lo staging: 2048 x 16B
    #pragma unroll
    for (int it = 0; it < 8; ++it) {
      int idx = tid + it * 256;
      int half = idx >> 10;
      int rem = idx & 1023;
      int d = rem >> 3, seg = rem & 7;
      const short* src = (half ? vloT : vhiT) + ((size_t)bh * D_ + d) * T_ + s0 + seg * 8;
      char* dst = (half ? Vl : Vh) + d * 136 + seg * 16;
      *(uint4*)dst = *(const uint4*)src;
    }
    __syncthreads();   // RAW: V tile visible

    const int8_t* kb = kq + ((size_t)bh * T_ + s0) * D_;
    const float*  skb = sk + (size_t)bh * T_ + s0;
    #pragma unroll
    for (int kt = 0; kt < 4; ++kt) {
      const int key = kt * 16 + l15;
      i32x4 b0 = *(const i32x4*)(kb + (size_t)key * D_ + quad * 16);
      i32x4 b1 = *(const i32x4*)(kb + (size_t)key * D_ + 64 + quad * 16);
      const float skc = skb[key];
      #pragma unroll
      for (int qt = 0; qt < 2; ++qt) {
        i32x4 c = i32x4{0, 0, 0, 0};
        c = mfma_i8(aq[qt][0], b0, c);
        c = mfma_i8(aq[qt][1], b1, c);
        #pragma unroll
        for (int r = 0; r < 4; ++r) {
          float t = (float)c[r] * skc;
          float wu = fast_exp2(fmaf(t, f1[qt][r], g[qt][r]));  // = 127*exp(s-m)
          zacc[qt][r] += wu;
          float wq = rintf(wu);                                 // integer in [0,127]
          short hb = (short)(__float_as_uint(wq) >> 16);        // exact bf16
          WsS[(32 * w + qt * 16 + quad * 4 + r) * 68 + key] = hb;
        }
      }
    }
    __threadfence_block();   // wave-private W rows: LDS drain only, no barrier
    // PV
    #pragma unroll
    for (int kc = 0; kc < 2; ++kc) {
      s16x8 a0 = *(const s16x8*)(Wsb + (32 * w + l15) * 136 + kc * 64 + quad * 16);
      s16x8 a1 = *(const s16x8*)(Wsb + (32 * w + 16 + l15) * 136 + kc * 64 + quad * 16);
      #pragma unroll
      for (int dt = 0; dt < 8; ++dt) {
        s16x8 vh = *(const s16x8*)(Vh + (dt * 16 + l15) * 136 + kc * 64 + quad * 16);
        s16x8 vl = *(const s16x8*)(Vl + (dt * 16 + l15) * 136 + kc * 64 + quad * 16);
        yacc[0][dt] = mfma_bf16(a0, vh, yacc[0][dt]);
        yacc[0][dt] = mfma_bf16(a0, vl, yacc[0][dt]);
        yacc[1][dt] = mfma_bf16(a1, vh, yacc[1][dt]);
        yacc[1][dt] = mfma_bf16(a1, vl, yacc[1][dt]);
      }
    }
  }

  #pragma unroll
  for (int mm = 1; mm < 16; mm <<= 1)
    #pragma unroll
    for (int qt = 0; qt < 2; ++qt)
      #pragma unroll
      for (int r = 0; r < 4; ++r)
        zacc[qt][r] += __shfl_xor(zacc[qt][r], mm, 64);

  // ---- epilogue: y = yacc/zacc (zacc = 127Z), per-(token,head) act_quant ----
  const int b = bh >> 4;
  const int h = bh & 15;
  #pragma unroll
  for (int qt = 0; qt < 2; ++qt)
    #pragma unroll
    for (int r = 0; r < 4; ++r) {
      float ym = 0.f;
      #pragma unroll
      for (int dt = 0; dt < 8; ++dt) ym = fmaxf(ym, fabsf(yacc[qt][dt][r]));
      #pragma unroll
      for (int mm = 1; mm < 16; mm <<= 1) ym = fmaxf(ym, __shfl_xor(ym, mm, 64));
      const float invz = 1.f / zacc[qt][r];
      const float ymt = fmaxf(ym * invz, EPSF);
      const float fs = 127.f / ymt;
      const int tglob = t0 + 32 * w + qt * 16 + quad * 4 + r;
      const size_t rowbase = ((size_t)(b * T_ + tglob)) * C_ + h * D_;
      #pragma unroll
      for (int dt = 0; dt < 8; ++dt) {
        float yv = yacc[qt][dt][r] * invz;
        float qv = fminf(fmaxf(rintf(yv * fs), -128.f), 127.f);
        yq[rowbase + dt * 16 + l15] = (int8_t)qv;
      }
      if (l15 == 0)
        sy[(size_t)(b * T_ + tglob) * H_ + h] = ymt / 127.f;
    }
}

// ---------------- output projection: i8 MFMA, LDS-staged (R2-proven) -----------------
// grid (C/64, R/128). Wave tile 64x32; int32 acc per head, folded every 2 K-chunks.
__global__ __launch_bounds__(256) void outproj_mfma_kernel(
    const int8_t* __restrict__ yq, const float* __restrict__ sy,
    const int8_t* __restrict__ Wt, const float* __restrict__ sw4,
    float* __restrict__ outp)
{
  const int n0  = blockIdx.x * 64;
  const int r0  = blockIdx.y * 128;
  const int tid = (int)threadIdx.x;
  const int wv   = tid >> 6;
  const int lane = tid & 63;
  const int quad = lane >> 4;
  const int l15  = lane & 15;
  const int rh   = wv >> 1, ch = wv & 1;
  const int8_t* Wm = Wt + (size_t)3 * C_ * C_;

  __shared__ __align__(16) char As[128 * 80];
  __shared__ __align__(16) char Bs[64 * 80];
  __shared__ float sYs[128][16];
  for (int idx = tid; idx < 128 * 16; idx += 256)
    sYs[idx >> 4][idx & 15] = sy[(size_t)(r0 + (idx >> 4)) * H_ + (idx & 15)];

  i32x4 iacc[4][2];
  f32x4 facc[4][2];
  #pragma unroll
  for (int i = 0; i < 4; ++i)
    #pragma unroll
    for (int j = 0; j < 2; ++j) { iacc[i][j] = i32x4{0,0,0,0}; facc[i][j] = f32x4{0.f,0.f,0.f,0.f}; }

  for (int kc = 0; kc < 32; ++kc) {
    const int k0 = kc * 64;
    #pragma unroll
    for (int it = 0; it < 2; ++it) {
      int idx = tid + it * 256;
      int row = idx >> 2, seg = idx & 3;
      *(uint4*)(As + row * 80 + seg * 16) =
          *(const uint4*)(yq + (size_t)(r0 + row) * C_ + k0 + seg * 16);
    }
    {
      int col = tid >> 2, seg = tid & 3;
      *(uint4*)(Bs + col * 80 + seg * 16) =
          *(const uint4*)(Wm + (size_t)(n0 + col) * C_ + k0 + seg * 16);
    }
    __syncthreads();
    i32x4 a[4], b[2];
    #pragma unroll
    for (int rt = 0; rt < 4; ++rt)
      a[rt] = *(const i32x4*)(As + (rh * 64 + rt * 16 + l15) * 80 + quad * 16);
    #pragma unroll
    for (int ct = 0; ct < 2; ++ct)
      b[ct] = *(const i32x4*)(Bs + (ch * 32 + ct * 16 + l15) * 80 + quad * 16);
    #pragma unroll
    for (int rt = 0; rt < 4; ++rt)
      #pragma unroll
      for (int ct = 0; ct < 2; ++ct)
        iacc[rt][ct] = mfma_i8(a[rt], b[ct], iacc[rt][ct]);
    __syncthreads();
    if (kc & 1) {
      const int hd = kc >> 1;
      #pragma unroll
      for (int rt = 0; rt < 4; ++rt)
        #pragma unroll
        for (int r = 0; r < 4; ++r) {
          const float s = sYs[rh * 64 + rt * 16 + quad * 4 + r][hd];
          #pragma unroll
          for (int ct = 0; ct < 2; ++ct)
            facc[rt][ct][r] += (float)iacc[rt][ct][r] * s;
        }
      #pragma unroll
      for (int rt = 0; rt < 4; ++rt)
        #pragma unroll
        for (int ct = 0; ct < 2; ++ct) iacc[rt][ct] = i32x4{0,0,0,0};
    }
  }
  const float swp = sw4[3];
  #pragma unroll
  for (int rt = 0; rt < 4; ++rt)
    #pragma unroll
    for (int r = 0; r < 4; ++r) {
      const int rowl = rh * 64 + rt * 16 + quad * 4 + r;
      #pragma unroll
      for (int ct = 0; ct < 2; ++ct)
        outp[(size_t)(r0 + rowl) * C_ + n0 + ch * 32 + ct * 16 + l15] =
            facc[rt][ct][r] * swp;
    }
}

// ---------------- final per-token act_quant ----------------
__global__ __launch_bounds__(256) void final_quant_kernel(
    const float* __restrict__ outp, float* __restrict__ out)
{
  const int r = blockIdx.x;
  const float* xr = outp + (size_t)r * C_;
  float am = 0.f;
  for (int j = threadIdx.x; j < C_; j += 256) am = fmaxf(am, fabsf(xr[j]));
  __shared__ float sm[256];
  sm[threadIdx.x] = am;
  __syncthreads();
  for (int o = 128; o > 0; o >>= 1) {
    if ((int)threadIdx.x < o) sm[threadIdx.x] = fmaxf(sm[threadIdx.x], sm[threadIdx.x + o]);
    __syncthreads();
  }
  const float m = fmaxf(sm[0], EPSF);
  const float scale = 127.f / m;
  const float inv = m / 127.f;
  for (int j = threadIdx.x; j < C_; j += 256) {
    float q = fminf(fmaxf(rintf(xr[j] * scale), -128.f), 127.f);
    out[(size_t)r * C_ + j] = q * inv;
  }
}

} // namespace

extern "C" void kernel_launch(void* const* d_in, const int* in_sizes, int n_in,
                              void* d_out, int out_size, void* d_ws, size_t ws_size,
                              hipStream_t stream)
{
  (void)in_sizes; (void)n_in; (void)out_size; (void)ws_size;
  const float* x  = (const float*)d_in[0];
  const float* W0 = (const float*)d_in[1];
  const float* W1 = (const float*)d_in[2];
  const float* W2 = (const float*)d_in[3];
  const float* W3 = (const float*)d_in[4];

  char* ws = (char*)d_ws;
  double* wsum = (double*)(ws + OFF_WSUM);
  float*  swv  = (float*) (ws + OFF_SW);
  int8_t* Wt   = (int8_t*)(ws + OFF_WT);
  int8_t* xq   = (int8_t*)(ws + OFF_XQ);
  float*  sx   = (float*) (ws + OFF_SX);
  int8_t* qkv  = (int8_t*)(ws + OFF_QKV);
  float*  sqkv = (float*) (ws + OFF_SQKV);
  int8_t* yqp  = (int8_t*)(ws + OFF_YQ);
  float*  syp  = (float*) (ws + OFF_SY);
  float*  outp = (float*) (ws + OFF_OUTP);
  short*  vhiT = (short*) (ws + OFF_VHI);          // aliases outp
  short*  vloT = vhiT + VT_ELEMS;

  hipMemsetAsync(d_ws, 0, 256, stream);
  hipLaunchKernelGGL(wabs_sum_kernel, dim3(256), dim3(256), 0, stream, W0, W1, W2, W3, wsum);
  hipLaunchKernelGGL(wquant_kernel, dim3(4096), dim3(256), 0, stream, W0, W1, W2, W3, wsum, Wt, swv);
  hipLaunchKernelGGL(xquant_kernel, dim3(R_), dim3(256), 0, stream, x, xq, sx);
  hipLaunchKernelGGL(proj_mfma_kernel, dim3(H_, R_ / 128, 3), dim3(256), 0, stream,
                     xq, sx, Wt, swv, qkv, sqkv);
  hipLaunchKernelGGL(vtrans_kernel, dim3(T_ / 64, B_ * H_), dim3(256), 0, stream,
                     qkv + (size_t)2 * R_ * C_, sqkv + (size_t)2 * R_ * H_, vhiT, vloT);
  hipLaunchKernelGGL(attn_mfma_kernel, dim3(B_ * H_, T_ / 128), dim3(256), 0, stream,
                     qkv, qkv + (size_t)R_ * C_,
                     sqkv, sqkv + (size_t)R_ * H_,
                     vhiT, vloT, yqp, syp);
  hipLaunchKernelGGL(outproj_mfma_kernel, dim3(C_ / 64, R_ / 128), dim3(256), 0, stream,
                     yqp, syp, Wt, swv, outp);
  hipLaunchKernelGGL(final_quant_kernel, dim3(R_), dim3(256), 0, stream, outp, (float*)d_out);
}

// Round 6
// 881.248 us; speedup vs baseline: 1.0420x; 1.0420x over previous
//
#include <hip/hip_runtime.h>
#include <stdint.h>

namespace {

constexpr int B_ = 2, T_ = 2048, C_ = 2048, H_ = 16, D_ = 128;
constexpr int R_ = B_ * T_;                 // 4096 token rows (b*T + t)
constexpr float EPSF = 1e-5f;
constexpr float INV_SQRT_D = 0.08838834764831845f;   // 1/sqrt(128)
constexpr float LOG2E = 1.4426950408889634f;
constexpr float LOG2_127 = 6.988684686772166f;

// ---- workspace layout (bytes) ----
constexpr size_t OFF_WSUM = 0;                                   // double[4]
constexpr size_t OFF_SW   = 64;                                  // float[4]
constexpr size_t OFF_WT   = 256;                                 // int8[4][C*C] ternary
constexpr size_t OFF_XQ   = OFF_WT   + (size_t)4 * C_ * C_;      // int8[R*C]
constexpr size_t OFF_SX   = OFF_XQ   + (size_t)R_ * C_;          // float[R]
constexpr size_t OFF_QKV  = OFF_SX   + (size_t)R_ * 4;           // int8[3][B*H*T*D]
constexpr size_t OFF_SQKV = OFF_QKV  + (size_t)3 * R_ * C_;      // float[3][B*H*T]
constexpr size_t OFF_YQ   = OFF_SQKV + (size_t)3 * R_ * H_ * 4;  // int8[R*C]
constexpr size_t OFF_SY   = OFF_YQ   + (size_t)R_ * C_;          // float[R*H]
constexpr size_t OFF_OUTP = OFF_SY   + (size_t)R_ * H_ * 4;      // float[R*C]
// vhiT/vloT (bf16 [bh][d][t], 16.78 MB each) alias OUTP (33.55 MB): dead before
// outproj writes outp (stream-ordered), so no extra workspace.
constexpr size_t OFF_VHI  = OFF_OUTP;
constexpr size_t VT_ELEMS = (size_t)B_ * H_ * D_ * T_;

typedef int   i32x4 __attribute__((ext_vector_type(4)));
typedef short s16x8 __attribute__((ext_vector_type(8)));
typedef float f32x4 __attribute__((ext_vector_type(4)));

__device__ __forceinline__ i32x4 mfma_i8(i32x4 a, i32x4 b, i32x4 c) {
  return __builtin_amdgcn_mfma_i32_16x16x64_i8(a, b, c, 0, 0, 0);
}
__device__ __forceinline__ f32x4 mfma_bf16(s16x8 a, s16x8 b, f32x4 c) {
  return __builtin_amdgcn_mfma_f32_16x16x32_bf16(a, b, c, 0, 0, 0);
}

// async global->LDS DMA, 16B per lane; LDS dest = wave-uniform base + lane*16
__device__ __forceinline__ void dma16(const void* g, void* l) {
  __builtin_amdgcn_global_load_lds(
      (const __attribute__((address_space(1))) void*)g,
      (__attribute__((address_space(3))) void*)l, 16, 0, 0);
}

#if __has_builtin(__builtin_amdgcn_exp2f)
__device__ __forceinline__ float fast_exp2(float x) { return __builtin_amdgcn_exp2f(x); }
#else
__device__ __forceinline__ float fast_exp2(float x) { return exp2f(x); }
#endif

// RTNE float->bf16 bits (matches numpy RTNE)
__device__ __forceinline__ short f2bf(float f) {
  union { float f; uint32_t u; } v; v.f = f;
  uint32_t r = v.u + 0x7fffu + ((v.u >> 16) & 1u);
  return (short)(r >> 16);
}
__device__ __forceinline__ float bf2f(short h) {
  union { uint32_t u; float f; } v; v.u = ((uint32_t)(uint16_t)h) << 16;
  return v.f;
}

// ---------------- mean(|W|) for the 4 weight matrices (double accum) ----------------
__global__ __launch_bounds__(256) void wabs_sum_kernel(
    const float* __restrict__ W0, const float* __restrict__ W1,
    const float* __restrict__ W2, const float* __restrict__ W3,
    double* __restrict__ wsum)
{
  const int w   = blockIdx.x >> 6;
  const int blk = blockIdx.x & 63;
  const float* W = (w == 0) ? W0 : (w == 1) ? W1 : (w == 2) ? W2 : W3;
  const int n = C_ * C_;
  double s = 0.0;
  for (int i = blk * 256 + (int)threadIdx.x; i < n; i += 64 * 256)
    s += (double)fabsf(W[i]);
  __shared__ double sm[256];
  sm[threadIdx.x] = s;
  __syncthreads();
  for (int o = 128; o > 0; o >>= 1) {
    if ((int)threadIdx.x < o) sm[threadIdx.x] += sm[threadIdx.x + o];
    __syncthreads();
  }
  if (threadIdx.x == 0) atomicAdd(&wsum[w], sm[0]);
}

// ---------------- ternary weight quant ----------------
__global__ __launch_bounds__(256) void wquant_kernel(
    const float* __restrict__ W0, const float* __restrict__ W1,
    const float* __restrict__ W2, const float* __restrict__ W3,
    const double* __restrict__ wsum, int8_t* __restrict__ Wt, float* __restrict__ sw)
{
  const int w = blockIdx.x >> 10;
  const float* W = (w == 0) ? W0 : (w == 1) ? W1 : (w == 2) ? W2 : W3;
  const int n = C_ * C_;
  const float s = fmaxf((float)(wsum[w] * (1.0 / (double)n)), EPSF);
  int8_t* dst = Wt + (size_t)w * n;
  const int base = (blockIdx.x & 1023) * 256 + (int)threadIdx.x;
  for (int i = base; i < n; i += 1024 * 256) {
    float t = rintf(W[i] / s);
    t = fminf(fmaxf(t, -1.f), 1.f);
    dst[i] = (int8_t)t;
  }
  if (base == 0) sw[w] = s;
}

// ---------------- per-token act_quant of x ----------------
__global__ __launch_bounds__(256) void xquant_kernel(
    const float* __restrict__ x, int8_t* __restrict__ xq, float* __restrict__ sx)
{
  const int r = blockIdx.x;
  const float* xr = x + (size_t)r * C_;
  float am = 0.f;
  for (int j = threadIdx.x; j < C_; j += 256) am = fmaxf(am, fabsf(xr[j]));
  __shared__ float sm[256];
  sm[threadIdx.x] = am;
  __syncthreads();
  for (int o = 128; o > 0; o >>= 1) {
    if ((int)threadIdx.x < o) sm[threadIdx.x] = fmaxf(sm[threadIdx.x], sm[threadIdx.x + o]);
    __syncthreads();
  }
  const float m = fmaxf(sm[0], EPSF);
  const float scale = 127.f / m;
  for (int j = threadIdx.x; j < C_; j += 256) {
    float q = fminf(fmaxf(rintf(xr[j] * scale), -128.f), 127.f);
    xq[(size_t)r * C_ + j] = (int8_t)q;
  }
  if (threadIdx.x == 0) sx[r] = m / 127.f;
}

// ---------------- q/k/v projection: i8 MFMA, async-DMA double-buffered LDS -----------
// grid (16 heads, R/128, 3). Block tile 128x128 (one head), wave 64x64 = 4x4 tiles.
// Staging via global_load_lds (16B/lane, async): one barrier per K-chunk; the DMA for
// chunk k+1 issues after the barrier and overlaps chunk k's MFMAs; the next barrier's
// implicit vmcnt(0) is the wait. Slot layout XOR-swizzled: slot = row*4+(quad^(row&3))
// -> global fetch stays 64B-coalesced per row, LDS fragment reads 2-way (free).
__global__ __launch_bounds__(256) void proj_mfma_kernel(
    const int8_t* __restrict__ xq, const float* __restrict__ sx,
    const int8_t* __restrict__ Wt, const float* __restrict__ sw4,
    int8_t* __restrict__ qkv, float* __restrict__ sqkv)
{
  const int h    = blockIdx.x;
  const int r0   = blockIdx.y * 128;
  const int wsel = blockIdx.z;
  const int tid  = (int)threadIdx.x;
  const int wv   = tid >> 6;
  const int lane = tid & 63;
  const int quad = lane >> 4;
  const int l15  = lane & 15;
  const int rh   = wv >> 1, ch = wv & 1;
  const int8_t* Wm = Wt + (size_t)wsel * C_ * C_;

  __shared__ __align__(16) char As[2][8192];   // 512 slots x 16B, swizzled
  __shared__ __align__(16) char Bs[2][8192];
  __shared__ int rmaxs[128];
  if (tid < 128) rmaxs[tid] = 0;

  // per-lane DMA source mapping for this wave's slot range
  const int s0a   = wv * 128;              // first slot of this wave's range
  const int rowA0 = (s0a + lane) >> 2;     // p=0 row
  const int qdA0  = ((s0a + lane) & 3) ^ (rowA0 & 3);
  const int rowA1 = (s0a + 64 + lane) >> 2;
  const int qdA1  = ((s0a + 64 + lane) & 3) ^ (rowA1 & 3);

  auto stage = [&](int bf, int k0) {
    dma16(xq + (size_t)(r0 + rowA0) * C_ + k0 + qdA0 * 16, &As[bf][(s0a) * 16]);
    dma16(xq + (size_t)(r0 + rowA1) * C_ + k0 + qdA1 * 16, &As[bf][(s0a + 64) * 16]);
    dma16(Wm + (size_t)(h * 128 + rowA0) * C_ + k0 + qdA0 * 16, &Bs[bf][(s0a) * 16]);
    dma16(Wm + (size_t)(h * 128 + rowA1) * C_ + k0 + qdA1 * 16, &Bs[bf][(s0a + 64) * 16]);
  };

  i32x4 acc[4][4];
  #pragma unroll
  for (int i = 0; i < 4; ++i)
    #pragma unroll
    for (int j = 0; j < 4; ++j) acc[i][j] = i32x4{0, 0, 0, 0};

  stage(0, 0);
  for (int kc = 0; kc < 32; ++kc) {
    __syncthreads();                       // vmcnt(0) drain: buf[kc&1] ready; prev compute done
    if (kc + 1 < 32) stage((kc + 1) & 1, (kc + 1) * 64);
    const char* Ab = As[kc & 1];
    const char* Bb = Bs[kc & 1];
    i32x4 a[4], b[4];
    #pragma unroll
    for (int rt = 0; rt < 4; ++rt) {
      const int row = rh * 64 + rt * 16 + l15;
      a[rt] = *(const i32x4*)(Ab + (row * 4 + (quad ^ (row & 3))) * 16);
    }
    #pragma unroll
    for (int ct = 0; ct < 4; ++ct) {
      const int col = ch * 64 + ct * 16 + l15;
      b[ct] = *(const i32x4*)(Bb + (col * 4 + (quad ^ (col & 3))) * 16);
    }
    #pragma unroll
    for (int rt = 0; rt < 4; ++rt)
      #pragma unroll
      for (int ct = 0; ct < 4; ++ct)
        acc[rt][ct] = mfma_i8(a[rt], b[ct], acc[rt][ct]);
  }

  // per-row abs-max over the full head via LDS atomicMax
  #pragma unroll
  for (int rt = 0; rt < 4; ++rt)
    #pragma unroll
    for (int r = 0; r < 4; ++r) {
      int m = 0;
      #pragma unroll
      for (int ct = 0; ct < 4; ++ct) {
        int v = acc[rt][ct][r];
        int av = v < 0 ? -v : v;
        m = m > av ? m : av;
      }
      #pragma unroll
      for (int mm = 1; mm < 16; mm <<= 1) {
        int o = __shfl_xor(m, mm, 64);
        m = m > o ? m : o;
      }
      if (l15 == 0) atomicMax(&rmaxs[rh * 64 + rt * 16 + quad * 4 + r], m);
    }
  __syncthreads();

  const float swv = sw4[wsel];
  #pragma unroll
  for (int rt = 0; rt < 4; ++rt)
    #pragma unroll
    for (int r = 0; r < 4; ++r) {
      const int rowl = rh * 64 + rt * 16 + quad * 4 + r;
      const int rglob = r0 + rowl;
      const int mN = rmaxs[rowl];
      const float qscale = (mN > 0) ? 127.f / (float)mN : 0.f;
      const int bb = rglob >> 11;
      const int tt = rglob & (T_ - 1);
      const size_t obase = ((size_t)(bb * H_ + h) * T_ + tt) * D_;
      #pragma unroll
      for (int ct = 0; ct < 4; ++ct) {
        const int col = ch * 64 + ct * 16 + l15;
        float q = rintf((float)acc[rt][ct][r] * qscale);
        q = fminf(fmaxf(q, -128.f), 127.f);
        qkv[(size_t)wsel * R_ * C_ + obase + col] = (int8_t)q;
      }
      if (ch == 0 && l15 == 0) {
        float maxq = (float)mN * sx[rglob] * swv;
        sqkv[(size_t)wsel * R_ * H_ + (size_t)(bb * H_ + h) * T_ + tt] =
            fmaxf(maxq, EPSF) / 127.f;
      }
    }
}

// ---------------- V dequant+transpose: int8 [bh][t][d] -> bf16 hi/lo [bh][d][t] ----------
__global__ __launch_bounds__(256) void vtrans_kernel(
    const int8_t* __restrict__ vq, const float* __restrict__ sv,
    short* __restrict__ vhiT, short* __restrict__ vloT)
{
  const int bh = blockIdx.y;
  const int s0 = blockIdx.x * 64;
  const int tid = (int)threadIdx.x;
  __shared__ __align__(16) int8_t Vs[64][144];
  __shared__ float svs[64];
  const int8_t* vbase = vq + ((size_t)bh * T_ + s0) * D_;
  #pragma unroll
  for (int it = 0; it < 2; ++it) {
    int idx = tid + it * 256;
    int row = idx >> 3, seg = idx & 7;
    *(uint4*)(&Vs[row][seg * 16]) = *(const uint4*)(vbase + row * 128 + seg * 16);
  }
  if (tid < 64) svs[tid] = sv[(size_t)bh * T_ + s0 + tid];
  __syncthreads();
  const int d = tid >> 1;
  const int kh = (tid & 1) * 32;
  uint32_t oh[16], ol[16];
  #pragma unroll
  for (int i = 0; i < 32; i += 2) {
    const int k0 = kh + i, k1 = kh + i + 1;
    float v0 = (float)(int)Vs[k0][d] * svs[k0];
    float v1 = (float)(int)Vs[k1][d] * svs[k1];
    short h0 = f2bf(v0), h1 = f2bf(v1);
    short l0 = f2bf(v0 - bf2f(h0)), l1 = f2bf(v1 - bf2f(h1));
    oh[i >> 1] = (uint32_t)(uint16_t)h0 | ((uint32_t)(uint16_t)h1 << 16);
    ol[i >> 1] = (uint32_t)(uint16_t)l0 | ((uint32_t)(uint16_t)l1 << 16);
  }
  const size_t dbase = ((size_t)bh * D_ + d) * T_ + s0 + kh;
  #pragma unroll
  for (int i = 0; i < 4; ++i) {
    uint4 a, b;
    a.x = oh[4 * i]; a.y = oh[4 * i + 1]; a.z = oh[4 * i + 2]; a.w = oh[4 * i + 3];
    b.x = ol[4 * i]; b.y = ol[4 * i + 1]; b.z = ol[4 * i + 2]; b.w = ol[4 * i + 3];
    *(uint4*)(vhiT + dbase + 8 * i) = a;
    *(uint4*)(vloT + dbase + 8 * i) = b;
  }
}

// ---------------- fused attention v6: R4 structure + stride 136 + reg prefetch -------
// grid (B*H, T/128). 4 waves x 32 q-rows. K/V/sks staged in LDS (2 barriers/chunk,
// R4-proven), but chunk k+1's staging data is loaded into REGISTERS right after the
// RAW barrier of chunk k -- global latency overlaps compute instead of the stage
// window. All LDS rows stride 136 B (measured conflict-free, R5). W integer weights
// (exact bf16) round-trip through wave-private LDS rows (fence only).
__global__ __launch_bounds__(256) void attn_mfma_kernel(
    const int8_t* __restrict__ qq, const int8_t* __restrict__ kq,
    const float* __restrict__ sq, const float* __restrict__ sk,
    const short* __restrict__ vhiT, const short* __restrict__ vloT,
    int8_t* __restrict__ yq, float* __restrict__ sy)
{
  const int bh  = blockIdx.x;
  const int t0  = blockIdx.y * 128;
  const int tid = (int)threadIdx.x;
  const int w    = tid >> 6;
  const int lane = tid & 63;
  const int quad = lane >> 4;
  const int l15  = lane & 15;

  __shared__ __align__(16) char smem[61184];
  char* Ks  = smem;            // [64 keys][136] int8 (128B data)
  char* Vh  = smem + 8704;     // [128 d][136] bf16 hi (64 keys)
  char* Vl  = smem + 26112;    // [128 d][136] bf16 lo
  char* Wsb = smem + 43520;    // [128 q][136] bf16 integer weights (64 keys)
  float* sks = (float*)(smem + 60928);
  short* WsS = (short*)Wsb;    // stride 68 shorts

  const int qrow0 = t0 + 32 * w;

  // Q A-frags + per-row scale factors, direct from global (read once)
  i32x4 aq[2][2];
  #pragma unroll
  for (int qt = 0; qt < 2; ++qt)
    #pragma unroll
    for (int hf = 0; hf < 2; ++hf)
      aq[qt][hf] = *(const i32x4*)(qq + ((size_t)bh * T_ + qrow0 + qt * 16 + l15) * D_ + hf * 64 + quad * 16);

  float f0[2][4];
  #pragma unroll
  for (int qt = 0; qt < 2; ++qt)
    #pragma unroll
    for (int r = 0; r < 4; ++r)
      f0[qt][r] = sq[(size_t)bh * T_ + qrow0 + qt * 16 + quad * 4 + r] * INV_SQRT_D;

  // staging-index precompute (same mapping for prefetch and LDS write)
  const int krow0 = tid >> 3,           kseg0 = tid & 7;          // K it=0
  const int krow1 = (tid + 256) >> 3,   kseg1 = (tid + 256) & 7;  // K it=1

  uint4 pk[2], pv[8];
  float psk = 0.f;

  auto prefetchK = [&](int sc) {
    const int8_t* kbase = kq + ((size_t)bh * T_ + sc) * D_;
    pk[0] = *(const uint4*)(kbase + krow0 * 128 + kseg0 * 16);
    pk[1] = *(const uint4*)(kbase + krow1 * 128 + kseg1 * 16);
    if (tid < 64) psk = sk[(size_t)bh * T_ + sc + tid];
  };
  auto writeK = [&]() {
    *(uint4*)(Ks + krow0 * 136 + kseg0 * 16) = pk[0];
    *(uint4*)(Ks + krow1 * 136 + kseg1 * 16) = pk[1];
    if (tid < 64) sks[tid] = psk;
  };
  auto prefetchV = [&](int sc) {
    #pragma unroll
    for (int it = 0; it < 8; ++it) {
      int idx = tid + it * 256;
      int half = idx >> 10;
      int rem = idx & 1023;
      int d = rem >> 3, seg = rem & 7;
      const short* src = (half ? vloT : vhiT) + ((size_t)bh * D_ + d) * T_ + sc + seg * 8;
      pv[it] = *(const uint4*)src;
    }
  };
  auto writeV = [&]() {
    #pragma unroll
    for (int it = 0; it < 8; ++it) {
      int idx = tid + it * 256;
      int half = idx >> 10;
      int rem = idx & 1023;
      int d = rem >> 3, seg = rem & 7;
      *(uint4*)((half ? Vl : Vh) + d * 136 + seg * 16) = pv[it];
    }
  };

  // ---- pass 1: exact rowmax of c*skc (positive f0 factored out) ----
  float rmaxc[2][4];
  #pragma unroll
  for (int qt = 0; qt < 2; ++qt)
    #pragma unroll
    for (int r = 0; r < 4; ++r) rmaxc[qt][r] = -3e38f;

  prefetchK(0);
  for (int s0 = 0; s0 < T_; s0 += 64) {
    __syncthreads();   // WAR vs previous chunk's K reads
    writeK();
    __syncthreads();   // RAW
    if (s0 + 64 < T_) prefetchK(s0 + 64);   // overlaps compute below
    #pragma unroll
    for (int kt = 0; kt < 4; ++kt) {
      const int key = kt * 16 + l15;
      i32x4 b0 = *(const i32x4*)(Ks + key * 136 + quad * 16);
      i32x4 b1 = *(const i32x4*)(Ks + key * 136 + 64 + quad * 16);
      const float skc = sks[key];
      #pragma unroll
      for (int qt = 0; qt < 2; ++qt) {
        i32x4 c = i32x4{0, 0, 0, 0};
        c = mfma_i8(aq[qt][0], b0, c);
        c = mfma_i8(aq[qt][1], b1, c);
        #pragma unroll
        for (int r = 0; r < 4; ++r)
          rmaxc[qt][r] = fmaxf(rmaxc[qt][r], (float)c[r] * skc);
      }
    }
  }
  // prefetch pass-2 chunk 0 now: overlaps the reductions below
  prefetchK(0);
  prefetchV(0);

  #pragma unroll
  for (int mm = 1; mm < 16; mm <<= 1)
    #pragma unroll
    for (int qt = 0; qt < 2; ++qt)
      #pragma unroll
      for (int r = 0; r < 4; ++r)
        rmaxc[qt][r] = fmaxf(rmaxc[qt][r], __shfl_xor(rmaxc[qt][r], mm, 64));

  float f1[2][4], g[2][4];
  #pragma unroll
  for (int qt = 0; qt < 2; ++qt)
    #pragma unroll
    for (int r = 0; r < 4; ++r) {
      f1[qt][r] = f0[qt][r] * LOG2E;
      g[qt][r]  = LOG2_127 - (rmaxc[qt][r] * f0[qt][r]) * LOG2E;
    }

  // ---- pass 2: quantized softmax + PV ----
  float zacc[2][4] = {};
  f32x4 yacc[2][8];
  #pragma unroll
  for (int qt = 0; qt < 2; ++qt)
    #pragma unroll
    for (int dt = 0; dt < 8; ++dt) yacc[qt][dt] = f32x4{0.f, 0.f, 0.f, 0.f};

  for (int s0 = 0; s0 < T_; s0 += 64) {
    __syncthreads();   // WAR: prev chunk's K/V reads complete
    writeK();
    writeV();
    __syncthreads();   // RAW: staging visible
    if (s0 + 64 < T_) { prefetchK(s0 + 64); prefetchV(s0 + 64); }  // overlap compute

    #pragma unroll
    for (int kt = 0; kt < 4; ++kt) {
      const int key = kt * 16 + l15;
      i32x4 b0 = *(const i32x4*)(Ks + key * 136 + quad * 16);
      i32x4 b1 = *(const i32x4*)(Ks + key * 136 + 64 + quad * 16);
      const float skc = sks[key];
      #pragma unroll
      for (int qt = 0; qt < 2; ++qt) {
        i32x4 c = i32x4{0, 0, 0, 0};
        c = mfma_i8(aq[qt][0], b0, c);
        c = mfma_i8(aq[qt][1], b1, c);
        #pragma unroll
        for (int r = 0; r < 4; ++r) {
          float t = (float)c[r] * skc;
          float wu = fast_exp2(fmaf(t, f1[qt][r], g[qt][r]));  // = 127*exp(s-m)
          zacc[qt][r] += wu;
          float wq = rintf(wu);                                 // integer in [0,127]
          short hb = (short)(__float_as_uint(wq) >> 16);        // exact bf16
          WsS[(32 * w + qt * 16 + quad * 4 + r) * 68 + key] = hb;
        }
      }
    }
    __threadfence_block();   // wave-private W rows: LDS drain only, no barrier
    // PV
    #pragma unroll
    for (int kc = 0; kc < 2; ++kc) {
      s16x8 a0 = *(const s16x8*)(Wsb + (32 * w + l15) * 136 + kc * 64 + quad * 16);
      s16x8 a1 = *(const s16x8*)(Wsb + (32 * w + 16 + l15) * 136 + kc * 64 + quad * 16);
      #pragma unroll
      for (int dt = 0; dt < 8; ++dt) {
        s16x8 vh = *(const s16x8*)(Vh + (dt * 16 + l15) * 136 + kc * 64 + quad * 16);
        s16x8 vl = *(const s16x8*)(Vl + (dt * 16 + l15) * 136 + kc * 64 + quad * 16);
        yacc[0][dt] = mfma_bf16(a0, vh, yacc[0][dt]);
        yacc[0][dt] = mfma_bf16(a0, vl, yacc[0][dt]);
        yacc[1][dt] = mfma_bf16(a1, vh, yacc[1][dt]);
        yacc[1][dt] = mfma_bf16(a1, vl, yacc[1][dt]);
      }
    }
  }

  #pragma unroll
  for (int mm = 1; mm < 16; mm <<= 1)
    #pragma unroll
    for (int qt = 0; qt < 2; ++qt)
      #pragma unroll
      for (int r = 0; r < 4; ++r)
        zacc[qt][r] += __shfl_xor(zacc[qt][r], mm, 64);

  // ---- epilogue: y = yacc/zacc (zacc = 127Z), per-(token,head) act_quant ----
  const int b = bh >> 4;
  const int h = bh & 15;
  #pragma unroll
  for (int qt = 0; qt < 2; ++qt)
    #pragma unroll
    for (int r = 0; r < 4; ++r) {
      float ym = 0.f;
      #pragma unroll
      for (int dt = 0; dt < 8; ++dt) ym = fmaxf(ym, fabsf(yacc[qt][dt][r]));
      #pragma unroll
      for (int mm = 1; mm < 16; mm <<= 1) ym = fmaxf(ym, __shfl_xor(ym, mm, 64));
      const float invz = 1.f / zacc[qt][r];
      const float ymt = fmaxf(ym * invz, EPSF);
      const float fs = 127.f / ymt;
      const int tglob = t0 + 32 * w + qt * 16 + quad * 4 + r;
      const size_t rowbase = ((size_t)(b * T_ + tglob)) * C_ + h * D_;
      #pragma unroll
      for (int dt = 0; dt < 8; ++dt) {
        float yv = yacc[qt][dt][r] * invz;
        float qv = fminf(fmaxf(rintf(yv * fs), -128.f), 127.f);
        yq[rowbase + dt * 16 + l15] = (int8_t)qv;
      }
      if (l15 == 0)
        sy[(size_t)(b * T_ + tglob) * H_ + h] = ymt / 127.f;
    }
}

// ---------------- output projection: i8 MFMA, LDS-staged (R2/R4-proven) --------------
// grid (C/64, R/128). Wave tile 64x32; int32 acc per head, folded every 2 K-chunks.
__global__ __launch_bounds__(256) void outproj_mfma_kernel(
    const int8_t* __restrict__ yq, const float* __restrict__ sy,
    const int8_t* __restrict__ Wt, const float* __restrict__ sw4,
    float* __restrict__ outp)
{
  const int n0  = blockIdx.x * 64;
  const int r0  = blockIdx.y * 128;
  const int tid = (int)threadIdx.x;
  const int wv   = tid >> 6;
  const int lane = tid & 63;
  const int quad = lane >> 4;
  const int l15  = lane & 15;
  const int rh   = wv >> 1, ch = wv & 1;
  const int8_t* Wm = Wt + (size_t)3 * C_ * C_;

  __shared__ __align__(16) char As[128 * 80];
  __shared__ __align__(16) char Bs[64 * 80];
  __shared__ float sYs[128][16];
  for (int idx = tid; idx < 128 * 16; idx += 256)
    sYs[idx >> 4][idx & 15] = sy[(size_t)(r0 + (idx >> 4)) * H_ + (idx & 15)];

  i32x4 iacc[4][2];
  f32x4 facc[4][2];
  #pragma unroll
  for (int i = 0; i < 4; ++i)
    #pragma unroll
    for (int j = 0; j < 2; ++j) { iacc[i][j] = i32x4{0,0,0,0}; facc[i][j] = f32x4{0.f,0.f,0.f,0.f}; }

  for (int kc = 0; kc < 32; ++kc) {
    const int k0 = kc * 64;
    #pragma unroll
    for (int it = 0; it < 2; ++it) {
      int idx = tid + it * 256;
      int row = idx >> 2, seg = idx & 3;
      *(uint4*)(As + row * 80 + seg * 16) =
          *(const uint4*)(yq + (size_t)(r0 + row) * C_ + k0 + seg * 16);
    }
    {
      int col = tid >> 2, seg = tid & 3;
      *(uint4*)(Bs + col * 80 + seg * 16) =
          *(const uint4*)(Wm + (size_t)(n0 + col) * C_ + k0 + seg * 16);
    }
    __syncthreads();
    i32x4 a[4], b[2];
    #pragma unroll
    for (int rt = 0; rt < 4; ++rt)
      a[rt] = *(const i32x4*)(As + (rh * 64 + rt * 16 + l15) * 80 + quad * 16);
    #pragma unroll
    for (int ct = 0; ct < 2; ++ct)
      b[ct] = *(const i32x4*)(Bs + (ch * 32 + ct * 16 + l15) * 80 + quad * 16);
    #pragma unroll
    for (int rt = 0; rt < 4; ++rt)
      #pragma unroll
      for (int ct = 0; ct < 2; ++ct)
        iacc[rt][ct] = mfma_i8(a[rt], b[ct], iacc[rt][ct]);
    __syncthreads();
    if (kc & 1) {
      const int hd = kc >> 1;
      #pragma unroll
      for (int rt = 0; rt < 4; ++rt)
        #pragma unroll
        for (int r = 0; r < 4; ++r) {
          const float s = sYs[rh * 64 + rt * 16 + quad * 4 + r][hd];
          #pragma unroll
          for (int ct = 0; ct < 2; ++ct)
            facc[rt][ct][r] += (float)iacc[rt][ct][r] * s;
        }
      #pragma unroll
      for (int rt = 0; rt < 4; ++rt)
        #pragma unroll
        for (int ct = 0; ct < 2; ++ct) iacc[rt][ct] = i32x4{0,0,0,0};
    }
  }
  const float swp = sw4[3];
  #pragma unroll
  for (int rt = 0; rt < 4; ++rt)
    #pragma unroll
    for (int r = 0; r < 4; ++r) {
      const int rowl = rh * 64 + rt * 16 + quad * 4 + r;
      #pragma unroll
      for (int ct = 0; ct < 2; ++ct)
        outp[(size_t)(r0 + rowl) * C_ + n0 + ch * 32 + ct * 16 + l15] =
            facc[rt][ct][r] * swp;
    }
}

// ---------------- final per-token act_quant ----------------
__global__ __launch_bounds__(256) void final_quant_kernel(
    const float* __restrict__ outp, float* __restrict__ out)
{
  const int r = blockIdx.x;
  const float* xr = outp + (size_t)r * C_;
  float am = 0.f;
  for (int j = threadIdx.x; j < C_; j += 256) am = fmaxf(am, fabsf(xr[j]));
  __shared__ float sm[256];
  sm[threadIdx.x] = am;
  __syncthreads();
  for (int o = 128; o > 0; o >>= 1) {
    if ((int)threadIdx.x < o) sm[threadIdx.x] = fmaxf(sm[threadIdx.x], sm[threadIdx.x + o]);
    __syncthreads();
  }
  const float m = fmaxf(sm[0], EPSF);
  const float scale = 127.f / m;
  const float inv = m / 127.f;
  for (int j = threadIdx.x; j < C_; j += 256) {
    float q = fminf(fmaxf(rintf(xr[j] * scale), -128.f), 127.f);
    out[(size_t)r * C_ + j] = q * inv;
  }
}

} // namespace

extern "C" void kernel_launch(void* const* d_in, const int* in_sizes, int n_in,
                              void* d_out, int out_size, void* d_ws, size_t ws_size,
                              hipStream_t stream)
{
  (void)in_sizes; (void)n_in; (void)out_size; (void)ws_size;
  const float* x  = (const float*)d_in[0];
  const float* W0 = (const float*)d_in[1];
  const float* W1 = (const float*)d_in[2];
  const float* W2 = (const float*)d_in[3];
  const float* W3 = (const float*)d_in[4];

  char* ws = (char*)d_ws;
  double* wsum = (double*)(ws + OFF_WSUM);
  float*  swv  = (float*) (ws + OFF_SW);
  int8_t* Wt   = (int8_t*)(ws + OFF_WT);
  int8_t* xq   = (int8_t*)(ws + OFF_XQ);
  float*  sx   = (float*) (ws + OFF_SX);
  int8_t* qkv  = (int8_t*)(ws + OFF_QKV);
  float*  sqkv = (float*) (ws + OFF_SQKV);
  int8_t* yqp  = (int8_t*)(ws + OFF_YQ);
  float*  syp  = (float*) (ws + OFF_SY);
  float*  outp = (float*) (ws + OFF_OUTP);
  short*  vhiT = (short*) (ws + OFF_VHI);          // aliases outp
  short*  vloT = vhiT + VT_ELEMS;

  hipMemsetAsync(d_ws, 0, 256, stream);
  hipLaunchKernelGGL(wabs_sum_kernel, dim3(256), dim3(256), 0, stream, W0, W1, W2, W3, wsum);
  hipLaunchKernelGGL(wquant_kernel, dim3(4096), dim3(256), 0, stream, W0, W1, W2, W3, wsum, Wt, swv);
  hipLaunchKernelGGL(xquant_kernel, dim3(R_), dim3(256), 0, stream, x, xq, sx);
  hipLaunchKernelGGL(proj_mfma_kernel, dim3(H_, R_ / 128, 3), dim3(256), 0, stream,
                     xq, sx, Wt, swv, qkv, sqkv);
  hipLaunchKernelGGL(vtrans_kernel, dim3(T_ / 64, B_ * H_), dim3(256), 0, stream,
                     qkv + (size_t)2 * R_ * C_, sqkv + (size_t)2 * R_ * H_, vhiT, vloT);
  hipLaunchKernelGGL(attn_mfma_kernel, dim3(B_ * H_, T_ / 128), dim3(256), 0, stream,
                     qkv, qkv + (size_t)R_ * C_,
                     sqkv, sqkv + (size_t)R_ * H_,
                     vhiT, vloT, yqp, syp);
  hipLaunchKernelGGL(outproj_mfma_kernel, dim3(C_ / 64, R_ / 128), dim3(256), 0, stream,
                     yqp, syp, Wt, swv, outp);
  hipLaunchKernelGGL(final_quant_kernel, dim3(R_), dim3(256), 0, stream, outp, (float*)d_out);
}

// Round 7
// 834.070 us; speedup vs baseline: 1.1010x; 1.0566x over previous
//
#include <hip/hip_runtime.h>
#include <stdint.h>

namespace {

constexpr int B_ = 2, T_ = 2048, C_ = 2048, H_ = 16, D_ = 128;
constexpr int R_ = B_ * T_;                 // 4096 token rows (b*T + t)
constexpr float EPSF = 1e-5f;
constexpr float INV_SQRT_D = 0.08838834764831845f;   // 1/sqrt(128)
constexpr float LOG2E = 1.4426950408889634f;
constexpr float LOG2_127 = 6.988684686772166f;

// ---- workspace layout (bytes) ----
constexpr size_t OFF_WSUM = 0;                                   // double[4]
constexpr size_t OFF_SW   = 64;                                  // float[4]
constexpr size_t OFF_WT   = 256;                                 // int8[4][C*C] ternary
constexpr size_t OFF_XQ   = OFF_WT   + (size_t)4 * C_ * C_;      // int8[R*C]
constexpr size_t OFF_SX   = OFF_XQ   + (size_t)R_ * C_;          // float[R]
constexpr size_t OFF_QKV  = OFF_SX   + (size_t)R_ * 4;           // int8[3][B*H*T*D]
constexpr size_t OFF_SQKV = OFF_QKV  + (size_t)3 * R_ * C_;      // float[3][B*H*T]
constexpr size_t OFF_YQ   = OFF_SQKV + (size_t)3 * R_ * H_ * 4;  // int8[R*C]
constexpr size_t OFF_SY   = OFF_YQ   + (size_t)R_ * C_;          // float[R*H]
constexpr size_t OFF_OUTP = OFF_SY   + (size_t)R_ * H_ * 4;      // float[R*C]
// vhiT/vloT (bf16 [bh][d][t], 16.78 MB each) alias OUTP (33.55 MB): dead before
// outproj writes outp (stream-ordered), so no extra workspace.
constexpr size_t OFF_VHI  = OFF_OUTP;
constexpr size_t VT_ELEMS = (size_t)B_ * H_ * D_ * T_;

typedef int   i32x4 __attribute__((ext_vector_type(4)));
typedef short s16x8 __attribute__((ext_vector_type(8)));
typedef float f32x4 __attribute__((ext_vector_type(4)));

__device__ __forceinline__ i32x4 mfma_i8(i32x4 a, i32x4 b, i32x4 c) {
  return __builtin_amdgcn_mfma_i32_16x16x64_i8(a, b, c, 0, 0, 0);
}
__device__ __forceinline__ f32x4 mfma_bf16(s16x8 a, s16x8 b, f32x4 c) {
  return __builtin_amdgcn_mfma_f32_16x16x32_bf16(a, b, c, 0, 0, 0);
}

// async global->LDS DMA, 16B per lane; LDS dest = wave-uniform base + lane*16
__device__ __forceinline__ void dma16(const void* g, void* l) {
  __builtin_amdgcn_global_load_lds(
      (const __attribute__((address_space(1))) void*)g,
      (__attribute__((address_space(3))) void*)l, 16, 0, 0);
}

#if __has_builtin(__builtin_amdgcn_exp2f)
__device__ __forceinline__ float fast_exp2(float x) { return __builtin_amdgcn_exp2f(x); }
#else
__device__ __forceinline__ float fast_exp2(float x) { return exp2f(x); }
#endif

// RTNE float->bf16 bits (matches numpy RTNE)
__device__ __forceinline__ short f2bf(float f) {
  union { float f; uint32_t u; } v; v.f = f;
  uint32_t r = v.u + 0x7fffu + ((v.u >> 16) & 1u);
  return (short)(r >> 16);
}
__device__ __forceinline__ float bf2f(short h) {
  union { uint32_t u; float f; } v; v.u = ((uint32_t)(uint16_t)h) << 16;
  return v.f;
}

// ---------------- mean(|W|) for the 4 weight matrices (double accum) ----------------
__global__ __launch_bounds__(256) void wabs_sum_kernel(
    const float* __restrict__ W0, const float* __restrict__ W1,
    const float* __restrict__ W2, const float* __restrict__ W3,
    double* __restrict__ wsum)
{
  const int w   = blockIdx.x >> 6;
  const int blk = blockIdx.x & 63;
  const float* W = (w == 0) ? W0 : (w == 1) ? W1 : (w == 2) ? W2 : W3;
  const int n = C_ * C_;
  double s = 0.0;
  for (int i = blk * 256 + (int)threadIdx.x; i < n; i += 64 * 256)
    s += (double)fabsf(W[i]);
  __shared__ double sm[256];
  sm[threadIdx.x] = s;
  __syncthreads();
  for (int o = 128; o > 0; o >>= 1) {
    if ((int)threadIdx.x < o) sm[threadIdx.x] += sm[threadIdx.x + o];
    __syncthreads();
  }
  if (threadIdx.x == 0) atomicAdd(&wsum[w], sm[0]);
}

// ---------------- ternary weight quant ----------------
__global__ __launch_bounds__(256) void wquant_kernel(
    const float* __restrict__ W0, const float* __restrict__ W1,
    const float* __restrict__ W2, const float* __restrict__ W3,
    const double* __restrict__ wsum, int8_t* __restrict__ Wt, float* __restrict__ sw)
{
  const int w = blockIdx.x >> 10;
  const float* W = (w == 0) ? W0 : (w == 1) ? W1 : (w == 2) ? W2 : W3;
  const int n = C_ * C_;
  const float s = fmaxf((float)(wsum[w] * (1.0 / (double)n)), EPSF);
  int8_t* dst = Wt + (size_t)w * n;
  const int base = (blockIdx.x & 1023) * 256 + (int)threadIdx.x;
  for (int i = base; i < n; i += 1024 * 256) {
    float t = rintf(W[i] / s);
    t = fminf(fmaxf(t, -1.f), 1.f);
    dst[i] = (int8_t)t;
  }
  if (base == 0) sw[w] = s;
}

// ---------------- per-token act_quant of x ----------------
__global__ __launch_bounds__(256) void xquant_kernel(
    const float* __restrict__ x, int8_t* __restrict__ xq, float* __restrict__ sx)
{
  const int r = blockIdx.x;
  const float* xr = x + (size_t)r * C_;
  float am = 0.f;
  for (int j = threadIdx.x; j < C_; j += 256) am = fmaxf(am, fabsf(xr[j]));
  __shared__ float sm[256];
  sm[threadIdx.x] = am;
  __syncthreads();
  for (int o = 128; o > 0; o >>= 1) {
    if ((int)threadIdx.x < o) sm[threadIdx.x] = fmaxf(sm[threadIdx.x], sm[threadIdx.x + o]);
    __syncthreads();
  }
  const float m = fmaxf(sm[0], EPSF);
  const float scale = 127.f / m;
  for (int j = threadIdx.x; j < C_; j += 256) {
    float q = fminf(fmaxf(rintf(xr[j] * scale), -128.f), 127.f);
    xq[(size_t)r * C_ + j] = (int8_t)q;
  }
  if (threadIdx.x == 0) sx[r] = m / 127.f;
}

// ---------------- q/k/v projection: i8 MFMA, async-DMA double-buffered LDS (R6-kept) -
// grid (16 heads, R/128, 3). Block tile 128x128 (one head), wave 64x64 = 4x4 tiles.
// Staging via global_load_lds (16B/lane, async): one barrier per K-chunk; the DMA for
// chunk k+1 issues after the barrier and overlaps chunk k's MFMAs.
__global__ __launch_bounds__(256) void proj_mfma_kernel(
    const int8_t* __restrict__ xq, const float* __restrict__ sx,
    const int8_t* __restrict__ Wt, const float* __restrict__ sw4,
    int8_t* __restrict__ qkv, float* __restrict__ sqkv)
{
  const int h    = blockIdx.x;
  const int r0   = blockIdx.y * 128;
  const int wsel = blockIdx.z;
  const int tid  = (int)threadIdx.x;
  const int wv   = tid >> 6;
  const int lane = tid & 63;
  const int quad = lane >> 4;
  const int l15  = lane & 15;
  const int rh   = wv >> 1, ch = wv & 1;
  const int8_t* Wm = Wt + (size_t)wsel * C_ * C_;

  __shared__ __align__(16) char As[2][8192];   // 512 slots x 16B, swizzled
  __shared__ __align__(16) char Bs[2][8192];
  __shared__ int rmaxs[128];
  if (tid < 128) rmaxs[tid] = 0;

  // per-lane DMA source mapping for this wave's slot range
  const int s0a   = wv * 128;              // first slot of this wave's range
  const int rowA0 = (s0a + lane) >> 2;     // p=0 row
  const int qdA0  = ((s0a + lane) & 3) ^ (rowA0 & 3);
  const int rowA1 = (s0a + 64 + lane) >> 2;
  const int qdA1  = ((s0a + 64 + lane) & 3) ^ (rowA1 & 3);

  auto stage = [&](int bf, int k0) {
    dma16(xq + (size_t)(r0 + rowA0) * C_ + k0 + qdA0 * 16, &As[bf][(s0a) * 16]);
    dma16(xq + (size_t)(r0 + rowA1) * C_ + k0 + qdA1 * 16, &As[bf][(s0a + 64) * 16]);
    dma16(Wm + (size_t)(h * 128 + rowA0) * C_ + k0 + qdA0 * 16, &Bs[bf][(s0a) * 16]);
    dma16(Wm + (size_t)(h * 128 + rowA1) * C_ + k0 + qdA1 * 16, &Bs[bf][(s0a + 64) * 16]);
  };

  i32x4 acc[4][4];
  #pragma unroll
  for (int i = 0; i < 4; ++i)
    #pragma unroll
    for (int j = 0; j < 4; ++j) acc[i][j] = i32x4{0, 0, 0, 0};

  stage(0, 0);
  for (int kc = 0; kc < 32; ++kc) {
    __syncthreads();                       // vmcnt(0) drain: buf[kc&1] ready; prev compute done
    if (kc + 1 < 32) stage((kc + 1) & 1, (kc + 1) * 64);
    const char* Ab = As[kc & 1];
    const char* Bb = Bs[kc & 1];
    i32x4 a[4], b[4];
    #pragma unroll
    for (int rt = 0; rt < 4; ++rt) {
      const int row = rh * 64 + rt * 16 + l15;
      a[rt] = *(const i32x4*)(Ab + (row * 4 + (quad ^ (row & 3))) * 16);
    }
    #pragma unroll
    for (int ct = 0; ct < 4; ++ct) {
      const int col = ch * 64 + ct * 16 + l15;
      b[ct] = *(const i32x4*)(Bb + (col * 4 + (quad ^ (col & 3))) * 16);
    }
    #pragma unroll
    for (int rt = 0; rt < 4; ++rt)
      #pragma unroll
      for (int ct = 0; ct < 4; ++ct)
        acc[rt][ct] = mfma_i8(a[rt], b[ct], acc[rt][ct]);
  }

  // per-row abs-max over the full head via LDS atomicMax
  #pragma unroll
  for (int rt = 0; rt < 4; ++rt)
    #pragma unroll
    for (int r = 0; r < 4; ++r) {
      int m = 0;
      #pragma unroll
      for (int ct = 0; ct < 4; ++ct) {
        int v = acc[rt][ct][r];
        int av = v < 0 ? -v : v;
        m = m > av ? m : av;
      }
      #pragma unroll
      for (int mm = 1; mm < 16; mm <<= 1) {
        int o = __shfl_xor(m, mm, 64);
        m = m > o ? m : o;
      }
      if (l15 == 0) atomicMax(&rmaxs[rh * 64 + rt * 16 + quad * 4 + r], m);
    }
  __syncthreads();

  const float swv = sw4[wsel];
  #pragma unroll
  for (int rt = 0; rt < 4; ++rt)
    #pragma unroll
    for (int r = 0; r < 4; ++r) {
      const int rowl = rh * 64 + rt * 16 + quad * 4 + r;
      const int rglob = r0 + rowl;
      const int mN = rmaxs[rowl];
      const float qscale = (mN > 0) ? 127.f / (float)mN : 0.f;
      const int bb = rglob >> 11;
      const int tt = rglob & (T_ - 1);
      const size_t obase = ((size_t)(bb * H_ + h) * T_ + tt) * D_;
      #pragma unroll
      for (int ct = 0; ct < 4; ++ct) {
        const int col = ch * 64 + ct * 16 + l15;
        float q = rintf((float)acc[rt][ct][r] * qscale);
        q = fminf(fmaxf(q, -128.f), 127.f);
        qkv[(size_t)wsel * R_ * C_ + obase + col] = (int8_t)q;
      }
      if (ch == 0 && l15 == 0) {
        float maxq = (float)mN * sx[rglob] * swv;
        sqkv[(size_t)wsel * R_ * H_ + (size_t)(bb * H_ + h) * T_ + tt] =
            fmaxf(maxq, EPSF) / 127.f;
      }
    }
}

// ---------------- V dequant+transpose: int8 [bh][t][d] -> bf16 hi/lo [bh][d][t] ----------
__global__ __launch_bounds__(256) void vtrans_kernel(
    const int8_t* __restrict__ vq, const float* __restrict__ sv,
    short* __restrict__ vhiT, short* __restrict__ vloT)
{
  const int bh = blockIdx.y;
  const int s0 = blockIdx.x * 64;
  const int tid = (int)threadIdx.x;
  __shared__ __align__(16) int8_t Vs[64][144];
  __shared__ float svs[64];
  const int8_t* vbase = vq + ((size_t)bh * T_ + s0) * D_;
  #pragma unroll
  for (int it = 0; it < 2; ++it) {
    int idx = tid + it * 256;
    int row = idx >> 3, seg = idx & 7;
    *(uint4*)(&Vs[row][seg * 16]) = *(const uint4*)(vbase + row * 128 + seg * 16);
  }
  if (tid < 64) svs[tid] = sv[(size_t)bh * T_ + s0 + tid];
  __syncthreads();
  const int d = tid >> 1;
  const int kh = (tid & 1) * 32;
  uint32_t oh[16], ol[16];
  #pragma unroll
  for (int i = 0; i < 32; i += 2) {
    const int k0 = kh + i, k1 = kh + i + 1;
    float v0 = (float)(int)Vs[k0][d] * svs[k0];
    float v1 = (float)(int)Vs[k1][d] * svs[k1];
    short h0 = f2bf(v0), h1 = f2bf(v1);
    short l0 = f2bf(v0 - bf2f(h0)), l1 = f2bf(v1 - bf2f(h1));
    oh[i >> 1] = (uint32_t)(uint16_t)h0 | ((uint32_t)(uint16_t)h1 << 16);
    ol[i >> 1] = (uint32_t)(uint16_t)l0 | ((uint32_t)(uint16_t)l1 << 16);
  }
  const size_t dbase = ((size_t)bh * D_ + d) * T_ + s0 + kh;
  #pragma unroll
  for (int i = 0; i < 4; ++i) {
    uint4 a, b;
    a.x = oh[4 * i]; a.y = oh[4 * i + 1]; a.z = oh[4 * i + 2]; a.w = oh[4 * i + 3];
    b.x = ol[4 * i]; b.y = ol[4 * i + 1]; b.z = ol[4 * i + 2]; b.w = ol[4 * i + 3];
    *(uint4*)(vhiT + dbase + 8 * i) = a;
    *(uint4*)(vloT + dbase + 8 * i) = b;
  }
}

// ---------------- fused attention v7: exact R4 structure, stride 136 -----------------
// grid (B*H, T/128). 4 waves x 32 q-rows. K staged in LDS (shared 4 waves); V hi/lo
// staged in LDS (read once per block); W integer weights (exact bf16, single piece)
// through wave-private LDS rows. All LDS rows stride 136 B (measured conflict-free).
// Softmax: wu = exp2(s*log2e + log2(127) - m*log2e); zacc accumulates 127Z directly;
// sv pre-folded into V (vtrans). NO register prefetch (R6: spills to scratch).
__global__ __launch_bounds__(256) void attn_mfma_kernel(
    const int8_t* __restrict__ qq, const int8_t* __restrict__ kq,
    const float* __restrict__ sq, const float* __restrict__ sk,
    const short* __restrict__ vhiT, const short* __restrict__ vloT,
    int8_t* __restrict__ yq, float* __restrict__ sy)
{
  const int bh  = blockIdx.x;
  const int t0  = blockIdx.y * 128;
  const int tid = (int)threadIdx.x;
  const int w    = tid >> 6;
  const int lane = tid & 63;
  const int quad = lane >> 4;
  const int l15  = lane & 15;

  __shared__ __align__(16) char smem[61184];
  char* Ks  = smem;            // [64 keys][136] int8 (128B data)
  char* Vh  = smem + 8704;     // [128 d][136] bf16 hi (64 keys)
  char* Vl  = smem + 26112;    // [128 d][136] bf16 lo
  char* Wsb = smem + 43520;    // [128 q][136] bf16 integer weights (64 keys)
  float* sks = (float*)(smem + 60928);
  short* WsS = (short*)Wsb;    // stride 68 shorts

  const int qrow0 = t0 + 32 * w;

  // Q A-frags + per-row scale factors, direct from global (read once)
  i32x4 aq[2][2];
  #pragma unroll
  for (int qt = 0; qt < 2; ++qt)
    #pragma unroll
    for (int hf = 0; hf < 2; ++hf)
      aq[qt][hf] = *(const i32x4*)(qq + ((size_t)bh * T_ + qrow0 + qt * 16 + l15) * D_ + hf * 64 + quad * 16);

  float f0[2][4];
  #pragma unroll
  for (int qt = 0; qt < 2; ++qt)
    #pragma unroll
    for (int r = 0; r < 4; ++r)
      f0[qt][r] = sq[(size_t)bh * T_ + qrow0 + qt * 16 + quad * 4 + r] * INV_SQRT_D;

  // ---- pass 1: exact rowmax of c*skc (positive f0 factored out) ----
  float rmaxc[2][4];
  #pragma unroll
  for (int qt = 0; qt < 2; ++qt)
    #pragma unroll
    for (int r = 0; r < 4; ++r) rmaxc[qt][r] = -3e38f;

  for (int s0 = 0; s0 < T_; s0 += 64) {
    __syncthreads();   // WAR vs previous chunk's K reads
    {
      const int8_t* kbase = kq + ((size_t)bh * T_ + s0) * D_;
      #pragma unroll
      for (int it = 0; it < 2; ++it) {
        int idx = tid + it * 256;
        int row = idx >> 3, seg = idx & 7;
        *(uint4*)(Ks + row * 136 + seg * 16) = *(const uint4*)(kbase + row * 128 + seg * 16);
      }
      if (tid < 64) sks[tid] = sk[(size_t)bh * T_ + s0 + tid];
    }
    __syncthreads();
    #pragma unroll
    for (int kt = 0; kt < 4; ++kt) {
      const int key = kt * 16 + l15;
      i32x4 b0 = *(const i32x4*)(Ks + key * 136 + quad * 16);
      i32x4 b1 = *(const i32x4*)(Ks + key * 136 + 64 + quad * 16);
      const float skc = sks[key];
      #pragma unroll
      for (int qt = 0; qt < 2; ++qt) {
        i32x4 c = i32x4{0, 0, 0, 0};
        c = mfma_i8(aq[qt][0], b0, c);
        c = mfma_i8(aq[qt][1], b1, c);
        #pragma unroll
        for (int r = 0; r < 4; ++r)
          rmaxc[qt][r] = fmaxf(rmaxc[qt][r], (float)c[r] * skc);
      }
    }
  }
  #pragma unroll
  for (int mm = 1; mm < 16; mm <<= 1)
    #pragma unroll
    for (int qt = 0; qt < 2; ++qt)
      #pragma unroll
      for (int r = 0; r < 4; ++r)
        rmaxc[qt][r] = fmaxf(rmaxc[qt][r], __shfl_xor(rmaxc[qt][r], mm, 64));

  float f1[2][4], g[2][4];
  #pragma unroll
  for (int qt = 0; qt < 2; ++qt)
    #pragma unroll
    for (int r = 0; r < 4; ++r) {
      f1[qt][r] = f0[qt][r] * LOG2E;
      g[qt][r]  = LOG2_127 - (rmaxc[qt][r] * f0[qt][r]) * LOG2E;
    }

  // ---- pass 2: quantized softmax + PV ----
  float zacc[2][4] = {};
  f32x4 yacc[2][8];
  #pragma unroll
  for (int qt = 0; qt < 2; ++qt)
    #pragma unroll
    for (int dt = 0; dt < 8; ++dt) yacc[qt][dt] = f32x4{0.f, 0.f, 0.f, 0.f};

  for (int s0 = 0; s0 < T_; s0 += 64) {
    __syncthreads();   // WAR: prev chunk's K/V reads complete
    {
      const int8_t* kbase = kq + ((size_t)bh * T_ + s0) * D_;
      #pragma unroll
      for (int it = 0; it < 2; ++it) {
        int idx = tid + it * 256;
        int row = idx >> 3, seg = idx & 7;
        *(uint4*)(Ks + row * 136 + seg * 16) = *(const uint4*)(kbase + row * 128 + seg * 16);
      }
      // V hi/lo: 2048 x 16B
      #pragma unroll
      for (int it = 0; it < 8; ++it) {
        int idx = tid + it * 256;
        int half = idx >> 10;
        int rem = idx & 1023;
        int d = rem >> 3, seg = rem & 7;
        const short* src = (half ? vloT : vhiT) + ((size_t)bh * D_ + d) * T_ + s0 + seg * 8;
        char* dst = (half ? Vl : Vh) + d * 136 + seg * 16;
        *(uint4*)dst = *(const uint4*)src;
      }
      if (tid < 64) sks[tid] = sk[(size_t)bh * T_ + s0 + tid];
    }
    __syncthreads();   // RAW: staging visible

    #pragma unroll
    for (int kt = 0; kt < 4; ++kt) {
      const int key = kt * 16 + l15;
      i32x4 b0 = *(const i32x4*)(Ks + key * 136 + quad * 16);
      i32x4 b1 = *(const i32x4*)(Ks + key * 136 + 64 + quad * 16);
      const float skc = sks[key];
      #pragma unroll
      for (int qt = 0; qt < 2; ++qt) {
        i32x4 c = i32x4{0, 0, 0, 0};
        c = mfma_i8(aq[qt][0], b0, c);
        c = mfma_i8(aq[qt][1], b1, c);
        #pragma unroll
        for (int r = 0; r < 4; ++r) {
          float t = (float)c[r] * skc;
          float wu = fast_exp2(fmaf(t, f1[qt][r], g[qt][r]));  // = 127*exp(s-m)
          zacc[qt][r] += wu;
          float wq = rintf(wu);                                 // integer in [0,127]
          short hb = (short)(__float_as_uint(wq) >> 16);        // exact bf16
          WsS[(32 * w + qt * 16 + quad * 4 + r) * 68 + key] = hb;
        }
      }
    }
    __threadfence_block();   // wave-private W rows: LDS drain only, no barrier
    // PV
    #pragma unroll
    for (int kc = 0; kc < 2; ++kc) {
      s16x8 a0 = *(const s16x8*)(Wsb + (32 * w + l15) * 136 + kc * 64 + quad * 16);
      s16x8 a1 = *(const s16x8*)(Wsb + (32 * w + 16 + l15) * 136 + kc * 64 + quad * 16);
      #pragma unroll
      for (int dt = 0; dt < 8; ++dt) {
        s16x8 vh = *(const s16x8*)(Vh + (dt * 16 + l15) * 136 + kc * 64 + quad * 16);
        s16x8 vl = *(const s16x8*)(Vl + (dt * 16 + l15) * 136 + kc * 64 + quad * 16);
        yacc[0][dt] = mfma_bf16(a0, vh, yacc[0][dt]);
        yacc[0][dt] = mfma_bf16(a0, vl, yacc[0][dt]);
        yacc[1][dt] = mfma_bf16(a1, vh, yacc[1][dt]);
        yacc[1][dt] = mfma_bf16(a1, vl, yacc[1][dt]);
      }
    }
  }

  #pragma unroll
  for (int mm = 1; mm < 16; mm <<= 1)
    #pragma unroll
    for (int qt = 0; qt < 2; ++qt)
      #pragma unroll
      for (int r = 0; r < 4; ++r)
        zacc[qt][r] += __shfl_xor(zacc[qt][r], mm, 64);

  // ---- epilogue: y = yacc/zacc (zacc = 127Z), per-(token,head) act_quant ----
  const int b = bh >> 4;
  const int h = bh & 15;
  #pragma unroll
  for (int qt = 0; qt < 2; ++qt)
    #pragma unroll
    for (int r = 0; r < 4; ++r) {
      float ym = 0.f;
      #pragma unroll
      for (int dt = 0; dt < 8; ++dt) ym = fmaxf(ym, fabsf(yacc[qt][dt][r]));
      #pragma unroll
      for (int mm = 1; mm < 16; mm <<= 1) ym = fmaxf(ym, __shfl_xor(ym, mm, 64));
      const float invz = 1.f / zacc[qt][r];
      const float ymt = fmaxf(ym * invz, EPSF);
      const float fs = 127.f / ymt;
      const int tglob = t0 + 32 * w + qt * 16 + quad * 4 + r;
      const size_t rowbase = ((size_t)(b * T_ + tglob)) * C_ + h * D_;
      #pragma unroll
      for (int dt = 0; dt < 8; ++dt) {
        float yv = yacc[qt][dt][r] * invz;
        float qv = fminf(fmaxf(rintf(yv * fs), -128.f), 127.f);
        yq[rowbase + dt * 16 + l15] = (int8_t)qv;
      }
      if (l15 == 0)
        sy[(size_t)(b * T_ + tglob) * H_ + h] = ymt / 127.f;
    }
}

// ---------------- output projection: i8 MFMA, LDS-staged (R2/R4-proven) --------------
// grid (C/64, R/128). Wave tile 64x32; int32 acc per head, folded every 2 K-chunks.
__global__ __launch_bounds__(256) void outproj_mfma_kernel(
    const int8_t* __restrict__ yq, const float* __restrict__ sy,
    const int8_t* __restrict__ Wt, const float* __restrict__ sw4,
    float* __restrict__ outp)
{
  const int n0  = blockIdx.x * 64;
  const int r0  = blockIdx.y * 128;
  const int tid = (int)threadIdx.x;
  const int wv   = tid >> 6;
  const int lane = tid & 63;
  const int quad = lane >> 4;
  const int l15  = lane & 15;
  const int rh   = wv >> 1, ch = wv & 1;
  const int8_t* Wm = Wt + (size_t)3 * C_ * C_;

  __shared__ __align__(16) char As[128 * 80];
  __shared__ __align__(16) char Bs[64 * 80];
  __shared__ float sYs[128][16];
  for (int idx = tid; idx < 128 * 16; idx += 256)
    sYs[idx >> 4][idx & 15] = sy[(size_t)(r0 + (idx >> 4)) * H_ + (idx & 15)];

  i32x4 iacc[4][2];
  f32x4 facc[4][2];
  #pragma unroll
  for (int i = 0; i < 4; ++i)
    #pragma unroll
    for (int j = 0; j < 2; ++j) { iacc[i][j] = i32x4{0,0,0,0}; facc[i][j] = f32x4{0.f,0.f,0.f,0.f}; }

  for (int kc = 0; kc < 32; ++kc) {
    const int k0 = kc * 64;
    #pragma unroll
    for (int it = 0; it < 2; ++it) {
      int idx = tid + it * 256;
      int row = idx >> 2, seg = idx & 3;
      *(uint4*)(As + row * 80 + seg * 16) =
          *(const uint4*)(yq + (size_t)(r0 + row) * C_ + k0 + seg * 16);
    }
    {
      int col = tid >> 2, seg = tid & 3;
      *(uint4*)(Bs + col * 80 + seg * 16) =
          *(const uint4*)(Wm + (size_t)(n0 + col) * C_ + k0 + seg * 16);
    }
    __syncthreads();
    i32x4 a[4], b[2];
    #pragma unroll
    for (int rt = 0; rt < 4; ++rt)
      a[rt] = *(const i32x4*)(As + (rh * 64 + rt * 16 + l15) * 80 + quad * 16);
    #pragma unroll
    for (int ct = 0; ct < 2; ++ct)
      b[ct] = *(const i32x4*)(Bs + (ch * 32 + ct * 16 + l15) * 80 + quad * 16);
    #pragma unroll
    for (int rt = 0; rt < 4; ++rt)
      #pragma unroll
      for (int ct = 0; ct < 2; ++ct)
        iacc[rt][ct] = mfma_i8(a[rt], b[ct], iacc[rt][ct]);
    __syncthreads();
    if (kc & 1) {
      const int hd = kc >> 1;
      #pragma unroll
      for (int rt = 0; rt < 4; ++rt)
        #pragma unroll
        for (int r = 0; r < 4; ++r) {
          const float s = sYs[rh * 64 + rt * 16 + quad * 4 + r][hd];
          #pragma unroll
          for (int ct = 0; ct < 2; ++ct)
            facc[rt][ct][r] += (float)iacc[rt][ct][r] * s;
        }
      #pragma unroll
      for (int rt = 0; rt < 4; ++rt)
        #pragma unroll
        for (int ct = 0; ct < 2; ++ct) iacc[rt][ct] = i32x4{0,0,0,0};
    }
  }
  const float swp = sw4[3];
  #pragma unroll
  for (int rt = 0; rt < 4; ++rt)
    #pragma unroll
    for (int r = 0; r < 4; ++r) {
      const int rowl = rh * 64 + rt * 16 + quad * 4 + r;
      #pragma unroll
      for (int ct = 0; ct < 2; ++ct)
        outp[(size_t)(r0 + rowl) * C_ + n0 + ch * 32 + ct * 16 + l15] =
            facc[rt][ct][r] * swp;
    }
}

// ---------------- final per-token act_quant ----------------
__global__ __launch_bounds__(256) void final_quant_kernel(
    const float* __restrict__ outp, float* __restrict__ out)
{
  const int r = blockIdx.x;
  const float* xr = outp + (size_t)r * C_;
  float am = 0.f;
  for (int j = threadIdx.x; j < C_; j += 256) am = fmaxf(am, fabsf(xr[j]));
  __shared__ float sm[256];
  sm[threadIdx.x] = am;
  __syncthreads();
  for (int o = 128; o > 0; o >>= 1) {
    if ((int)threadIdx.x < o) sm[threadIdx.x] = fmaxf(sm[threadIdx.x], sm[threadIdx.x + o]);
    __syncthreads();
  }
  const float m = fmaxf(sm[0], EPSF);
  const float scale = 127.f / m;
  const float inv = m / 127.f;
  for (int j = threadIdx.x; j < C_; j += 256) {
    float q = fminf(fmaxf(rintf(xr[j] * scale), -128.f), 127.f);
    out[(size_t)r * C_ + j] = q * inv;
  }
}

} // namespace

extern "C" void kernel_launch(void* const* d_in, const int* in_sizes, int n_in,
                              void* d_out, int out_size, void* d_ws, size_t ws_size,
                              hipStream_t stream)
{
  (void)in_sizes; (void)n_in; (void)out_size; (void)ws_size;
  const float* x  = (const float*)d_in[0];
  const float* W0 = (const float*)d_in[1];
  const float* W1 = (const float*)d_in[2];
  const float* W2 = (const float*)d_in[3];
  const float* W3 = (const float*)d_in[4];

  char* ws = (char*)d_ws;
  double* wsum = (double*)(ws + OFF_WSUM);
  float*  swv  = (float*) (ws + OFF_SW);
  int8_t* Wt   = (int8_t*)(ws + OFF_WT);
  int8_t* xq   = (int8_t*)(ws + OFF_XQ);
  float*  sx   = (float*) (ws + OFF_SX);
  int8_t* qkv  = (int8_t*)(ws + OFF_QKV);
  float*  sqkv = (float*) (ws + OFF_SQKV);
  int8_t* yqp  = (int8_t*)(ws + OFF_YQ);
  float*  syp  = (float*) (ws + OFF_SY);
  float*  outp = (float*) (ws + OFF_OUTP);
  short*  vhiT = (short*) (ws + OFF_VHI);          // aliases outp
  short*  vloT = vhiT + VT_ELEMS;

  hipMemsetAsync(d_ws, 0, 256, stream);
  hipLaunchKernelGGL(wabs_sum_kernel, dim3(256), dim3(256), 0, stream, W0, W1, W2, W3, wsum);
  hipLaunchKernelGGL(wquant_kernel, dim3(4096), dim3(256), 0, stream, W0, W1, W2, W3, wsum, Wt, swv);
  hipLaunchKernelGGL(xquant_kernel, dim3(R_), dim3(256), 0, stream, x, xq, sx);
  hipLaunchKernelGGL(proj_mfma_kernel, dim3(H_, R_ / 128, 3), dim3(256), 0, stream,
                     xq, sx, Wt, swv, qkv, sqkv);
  hipLaunchKernelGGL(vtrans_kernel, dim3(T_ / 64, B_ * H_), dim3(256), 0, stream,
                     qkv + (size_t)2 * R_ * C_, sqkv + (size_t)2 * R_ * H_, vhiT, vloT);
  hipLaunchKernelGGL(attn_mfma_kernel, dim3(B_ * H_, T_ / 128), dim3(256), 0, stream,
                     qkv, qkv + (size_t)R_ * C_,
                     sqkv, sqkv + (size_t)R_ * H_,
                     vhiT, vloT, yqp, syp);
  hipLaunchKernelGGL(outproj_mfma_kernel, dim3(C_ / 64, R_ / 128), dim3(256), 0, stream,
                     yqp, syp, Wt, swv, outp);
  hipLaunchKernelGGL(final_quant_kernel, dim3(R_), dim3(256), 0, stream, outp, (float*)d_out);
}

// Round 8
// 592.067 us; speedup vs baseline: 1.5510x; 1.4087x over previous
//
#include <hip/hip_runtime.h>
#include <stdint.h>

namespace {

constexpr int B_ = 2, T_ = 2048, C_ = 2048, H_ = 16, D_ = 128;
constexpr int R_ = B_ * T_;                 // 4096 token rows (b*T + t)
constexpr float EPSF = 1e-5f;
constexpr float INV_SQRT_D = 0.08838834764831845f;   // 1/sqrt(128)
constexpr float LOG2E = 1.4426950408889634f;
constexpr float LOG2_127 = 6.988684686772166f;

// ---- workspace layout (bytes) ----
constexpr size_t OFF_WSUM = 0;                                   // double[4]
constexpr size_t OFF_SW   = 64;                                  // float[4]
constexpr size_t OFF_WT   = 256;                                 // int8[4][C*C] ternary
constexpr size_t OFF_XQ   = OFF_WT   + (size_t)4 * C_ * C_;      // int8[R*C]
constexpr size_t OFF_SX   = OFF_XQ   + (size_t)R_ * C_;          // float[R]
constexpr size_t OFF_QKV  = OFF_SX   + (size_t)R_ * 4;           // int8[3][B*H*T*D]
constexpr size_t OFF_SQKV = OFF_QKV  + (size_t)3 * R_ * C_;      // float[3][B*H*T]
constexpr size_t OFF_YQ   = OFF_SQKV + (size_t)3 * R_ * H_ * 4;  // int8[R*C]
constexpr size_t OFF_SY   = OFF_YQ   + (size_t)R_ * C_;          // float[R*H]
constexpr size_t OFF_OUTP = OFF_SY   + (size_t)R_ * H_ * 4;      // float[R*C]
// vhiT/vloT (bf16 [bh][d][t], 16.78 MB each) alias OUTP (33.55 MB): dead before
// outproj writes outp (stream-ordered), so no extra workspace.
constexpr size_t OFF_VHI  = OFF_OUTP;
constexpr size_t VT_ELEMS = (size_t)B_ * H_ * D_ * T_;

typedef int   i32x4 __attribute__((ext_vector_type(4)));
typedef short s16x8 __attribute__((ext_vector_type(8)));
typedef float f32x4 __attribute__((ext_vector_type(4)));

__device__ __forceinline__ i32x4 mfma_i8(i32x4 a, i32x4 b, i32x4 c) {
  return __builtin_amdgcn_mfma_i32_16x16x64_i8(a, b, c, 0, 0, 0);
}
__device__ __forceinline__ f32x4 mfma_bf16(s16x8 a, s16x8 b, f32x4 c) {
  return __builtin_amdgcn_mfma_f32_16x16x32_bf16(a, b, c, 0, 0, 0);
}

// async global->LDS DMA, 16B per lane; LDS dest = wave-uniform base + lane*16
__device__ __forceinline__ void dma16(const void* g, void* l) {
  __builtin_amdgcn_global_load_lds(
      (const __attribute__((address_space(1))) void*)g,
      (__attribute__((address_space(3))) void*)l, 16, 0, 0);
}

#if __has_builtin(__builtin_amdgcn_exp2f)
__device__ __forceinline__ float fast_exp2(float x) { return __builtin_amdgcn_exp2f(x); }
#else
__device__ __forceinline__ float fast_exp2(float x) { return exp2f(x); }
#endif

// RTNE float->bf16 bits (matches numpy RTNE)
__device__ __forceinline__ short f2bf(float f) {
  union { float f; uint32_t u; } v; v.f = f;
  uint32_t r = v.u + 0x7fffu + ((v.u >> 16) & 1u);
  return (short)(r >> 16);
}
__device__ __forceinline__ float bf2f(short h) {
  union { uint32_t u; float f; } v; v.u = ((uint32_t)(uint16_t)h) << 16;
  return v.f;
}

// ---------------- mean(|W|) for the 4 weight matrices (double accum) ----------------
__global__ __launch_bounds__(256) void wabs_sum_kernel(
    const float* __restrict__ W0, const float* __restrict__ W1,
    const float* __restrict__ W2, const float* __restrict__ W3,
    double* __restrict__ wsum)
{
  const int w   = blockIdx.x >> 6;
  const int blk = blockIdx.x & 63;
  const float* W = (w == 0) ? W0 : (w == 1) ? W1 : (w == 2) ? W2 : W3;
  const int n = C_ * C_;
  double s = 0.0;
  for (int i = blk * 256 + (int)threadIdx.x; i < n; i += 64 * 256)
    s += (double)fabsf(W[i]);
  __shared__ double sm[256];
  sm[threadIdx.x] = s;
  __syncthreads();
  for (int o = 128; o > 0; o >>= 1) {
    if ((int)threadIdx.x < o) sm[threadIdx.x] += sm[threadIdx.x + o];
    __syncthreads();
  }
  if (threadIdx.x == 0) atomicAdd(&wsum[w], sm[0]);
}

// ---------------- ternary weight quant ----------------
__global__ __launch_bounds__(256) void wquant_kernel(
    const float* __restrict__ W0, const float* __restrict__ W1,
    const float* __restrict__ W2, const float* __restrict__ W3,
    const double* __restrict__ wsum, int8_t* __restrict__ Wt, float* __restrict__ sw)
{
  const int w = blockIdx.x >> 10;
  const float* W = (w == 0) ? W0 : (w == 1) ? W1 : (w == 2) ? W2 : W3;
  const int n = C_ * C_;
  const float s = fmaxf((float)(wsum[w] * (1.0 / (double)n)), EPSF);
  int8_t* dst = Wt + (size_t)w * n;
  const int base = (blockIdx.x & 1023) * 256 + (int)threadIdx.x;
  for (int i = base; i < n; i += 1024 * 256) {
    float t = rintf(W[i] / s);
    t = fminf(fmaxf(t, -1.f), 1.f);
    dst[i] = (int8_t)t;
  }
  if (base == 0) sw[w] = s;
}

// ---------------- per-token act_quant of x ----------------
__global__ __launch_bounds__(256) void xquant_kernel(
    const float* __restrict__ x, int8_t* __restrict__ xq, float* __restrict__ sx)
{
  const int r = blockIdx.x;
  const float* xr = x + (size_t)r * C_;
  float am = 0.f;
  for (int j = threadIdx.x; j < C_; j += 256) am = fmaxf(am, fabsf(xr[j]));
  __shared__ float sm[256];
  sm[threadIdx.x] = am;
  __syncthreads();
  for (int o = 128; o > 0; o >>= 1) {
    if ((int)threadIdx.x < o) sm[threadIdx.x] = fmaxf(sm[threadIdx.x], sm[threadIdx.x + o]);
    __syncthreads();
  }
  const float m = fmaxf(sm[0], EPSF);
  const float scale = 127.f / m;
  for (int j = threadIdx.x; j < C_; j += 256) {
    float q = fminf(fmaxf(rintf(xr[j] * scale), -128.f), 127.f);
    xq[(size_t)r * C_ + j] = (int8_t)q;
  }
  if (threadIdx.x == 0) sx[r] = m / 127.f;
}

// ---------------- q/k/v projection: i8 MFMA, async-DMA double-buffered LDS (R6-kept) -
// grid (16 heads, R/128, 3). Block tile 128x128 (one head), wave 64x64 = 4x4 tiles.
// Staging via global_load_lds (16B/lane, async): one barrier per K-chunk; the DMA for
// chunk k+1 issues after the barrier and overlaps chunk k's MFMAs.
__global__ __launch_bounds__(256) void proj_mfma_kernel(
    const int8_t* __restrict__ xq, const float* __restrict__ sx,
    const int8_t* __restrict__ Wt, const float* __restrict__ sw4,
    int8_t* __restrict__ qkv, float* __restrict__ sqkv)
{
  const int h    = blockIdx.x;
  const int r0   = blockIdx.y * 128;
  const int wsel = blockIdx.z;
  const int tid  = (int)threadIdx.x;
  const int wv   = tid >> 6;
  const int lane = tid & 63;
  const int quad = lane >> 4;
  const int l15  = lane & 15;
  const int rh   = wv >> 1, ch = wv & 1;
  const int8_t* Wm = Wt + (size_t)wsel * C_ * C_;

  __shared__ __align__(16) char As[2][8192];   // 512 slots x 16B, swizzled
  __shared__ __align__(16) char Bs[2][8192];
  __shared__ int rmaxs[128];
  if (tid < 128) rmaxs[tid] = 0;

  // per-lane DMA source mapping for this wave's slot range
  const int s0a   = wv * 128;              // first slot of this wave's range
  const int rowA0 = (s0a + lane) >> 2;     // p=0 row
  const int qdA0  = ((s0a + lane) & 3) ^ (rowA0 & 3);
  const int rowA1 = (s0a + 64 + lane) >> 2;
  const int qdA1  = ((s0a + 64 + lane) & 3) ^ (rowA1 & 3);

  auto stage = [&](int bf, int k0) {
    dma16(xq + (size_t)(r0 + rowA0) * C_ + k0 + qdA0 * 16, &As[bf][(s0a) * 16]);
    dma16(xq + (size_t)(r0 + rowA1) * C_ + k0 + qdA1 * 16, &As[bf][(s0a + 64) * 16]);
    dma16(Wm + (size_t)(h * 128 + rowA0) * C_ + k0 + qdA0 * 16, &Bs[bf][(s0a) * 16]);
    dma16(Wm + (size_t)(h * 128 + rowA1) * C_ + k0 + qdA1 * 16, &Bs[bf][(s0a + 64) * 16]);
  };

  i32x4 acc[4][4];
  #pragma unroll
  for (int i = 0; i < 4; ++i)
    #pragma unroll
    for (int j = 0; j < 4; ++j) acc[i][j] = i32x4{0, 0, 0, 0};

  stage(0, 0);
  for (int kc = 0; kc < 32; ++kc) {
    __syncthreads();                       // vmcnt(0) drain: buf[kc&1] ready; prev compute done
    if (kc + 1 < 32) stage((kc + 1) & 1, (kc + 1) * 64);
    const char* Ab = As[kc & 1];
    const char* Bb = Bs[kc & 1];
    i32x4 a[4], b[4];
    #pragma unroll
    for (int rt = 0; rt < 4; ++rt) {
      const int row = rh * 64 + rt * 16 + l15;
      a[rt] = *(const i32x4*)(Ab + (row * 4 + (quad ^ (row & 3))) * 16);
    }
    #pragma unroll
    for (int ct = 0; ct < 4; ++ct) {
      const int col = ch * 64 + ct * 16 + l15;
      b[ct] = *(const i32x4*)(Bb + (col * 4 + (quad ^ (col & 3))) * 16);
    }
    #pragma unroll
    for (int rt = 0; rt < 4; ++rt)
      #pragma unroll
      for (int ct = 0; ct < 4; ++ct)
        acc[rt][ct] = mfma_i8(a[rt], b[ct], acc[rt][ct]);
  }

  // per-row abs-max over the full head via LDS atomicMax
  #pragma unroll
  for (int rt = 0; rt < 4; ++rt)
    #pragma unroll
    for (int r = 0; r < 4; ++r) {
      int m = 0;
      #pragma unroll
      for (int ct = 0; ct < 4; ++ct) {
        int v = acc[rt][ct][r];
        int av = v < 0 ? -v : v;
        m = m > av ? m : av;
      }
      #pragma unroll
      for (int mm = 1; mm < 16; mm <<= 1) {
        int o = __shfl_xor(m, mm, 64);
        m = m > o ? m : o;
      }
      if (l15 == 0) atomicMax(&rmaxs[rh * 64 + rt * 16 + quad * 4 + r], m);
    }
  __syncthreads();

  const float swv = sw4[wsel];
  #pragma unroll
  for (int rt = 0; rt < 4; ++rt)
    #pragma unroll
    for (int r = 0; r < 4; ++r) {
      const int rowl = rh * 64 + rt * 16 + quad * 4 + r;
      const int rglob = r0 + rowl;
      const int mN = rmaxs[rowl];
      const float qscale = (mN > 0) ? 127.f / (float)mN : 0.f;
      const int bb = rglob >> 11;
      const int tt = rglob & (T_ - 1);
      const size_t obase = ((size_t)(bb * H_ + h) * T_ + tt) * D_;
      #pragma unroll
      for (int ct = 0; ct < 4; ++ct) {
        const int col = ch * 64 + ct * 16 + l15;
        float q = rintf((float)acc[rt][ct][r] * qscale);
        q = fminf(fmaxf(q, -128.f), 127.f);
        qkv[(size_t)wsel * R_ * C_ + obase + col] = (int8_t)q;
      }
      if (ch == 0 && l15 == 0) {
        float maxq = (float)mN * sx[rglob] * swv;
        sqkv[(size_t)wsel * R_ * H_ + (size_t)(bb * H_ + h) * T_ + tt] =
            fmaxf(maxq, EPSF) / 127.f;
      }
    }
}

// ---------------- V dequant+transpose: int8 [bh][t][d] -> bf16 hi/lo [bh][d][t] ----------
__global__ __launch_bounds__(256) void vtrans_kernel(
    const int8_t* __restrict__ vq, const float* __restrict__ sv,
    short* __restrict__ vhiT, short* __restrict__ vloT)
{
  const int bh = blockIdx.y;
  const int s0 = blockIdx.x * 64;
  const int tid = (int)threadIdx.x;
  __shared__ __align__(16) int8_t Vs[64][144];
  __shared__ float svs[64];
  const int8_t* vbase = vq + ((size_t)bh * T_ + s0) * D_;
  #pragma unroll
  for (int it = 0; it < 2; ++it) {
    int idx = tid + it * 256;
    int row = idx >> 3, seg = idx & 7;
    *(uint4*)(&Vs[row][seg * 16]) = *(const uint4*)(vbase + row * 128 + seg * 16);
  }
  if (tid < 64) svs[tid] = sv[(size_t)bh * T_ + s0 + tid];
  __syncthreads();
  const int d = tid >> 1;
  const int kh = (tid & 1) * 32;
  uint32_t oh[16], ol[16];
  #pragma unroll
  for (int i = 0; i < 32; i += 2) {
    const int k0 = kh + i, k1 = kh + i + 1;
    float v0 = (float)(int)Vs[k0][d] * svs[k0];
    float v1 = (float)(int)Vs[k1][d] * svs[k1];
    short h0 = f2bf(v0), h1 = f2bf(v1);
    short l0 = f2bf(v0 - bf2f(h0)), l1 = f2bf(v1 - bf2f(h1));
    oh[i >> 1] = (uint32_t)(uint16_t)h0 | ((uint32_t)(uint16_t)h1 << 16);
    ol[i >> 1] = (uint32_t)(uint16_t)l0 | ((uint32_t)(uint16_t)l1 << 16);
  }
  const size_t dbase = ((size_t)bh * D_ + d) * T_ + s0 + kh;
  #pragma unroll
  for (int i = 0; i < 4; ++i) {
    uint4 a, b;
    a.x = oh[4 * i]; a.y = oh[4 * i + 1]; a.z = oh[4 * i + 2]; a.w = oh[4 * i + 3];
    b.x = ol[4 * i]; b.y = ol[4 * i + 1]; b.z = ol[4 * i + 2]; b.w = ol[4 * i + 3];
    *(uint4*)(vhiT + dbase + 8 * i) = a;
    *(uint4*)(vloT + dbase + 8 * i) = b;
  }
}

// ---------------- fused attention v8: byte-exact R4 revert (best measured: 212 us) ---
// grid (B*H, T/128). 4 waves x 32 q-rows. K staged in LDS (shared 4 waves); V hi/lo
// staged in LDS (read once per block); W integer weights (exact bf16) round-trip
// through wave-private LDS rows (fence only). Row stride 144 B: 16B-ALIGNED (b128
// reads/writes stay single-instruction; 136 B broke alignment -> 2.2x regression, R7).
// Softmax: wu = exp2(s*log2e + log2(127) - m*log2e); zacc accumulates 127Z directly;
// sv pre-folded into V (vtrans). No register prefetch (R6: spills to scratch).
__global__ __launch_bounds__(256) void attn_mfma_kernel(
    const int8_t* __restrict__ qq, const int8_t* __restrict__ kq,
    const float* __restrict__ sq, const float* __restrict__ sk,
    const short* __restrict__ vhiT, const short* __restrict__ vloT,
    int8_t* __restrict__ yq, float* __restrict__ sy)
{
  const int bh  = blockIdx.x;
  const int t0  = blockIdx.y * 128;
  const int tid = (int)threadIdx.x;
  const int w    = tid >> 6;
  const int lane = tid & 63;
  const int quad = lane >> 4;
  const int l15  = lane & 15;

  __shared__ __align__(16) char smem[64768];
  char* Ks  = smem;            // [64 keys][144] int8 (128B data)
  char* Vh  = smem + 9216;     // [128 d][144] bf16 hi (64 keys)
  char* Vl  = smem + 27648;    // [128 d][144] bf16 lo
  char* Wsb = smem + 46080;    // [128 q][144] bf16 integer weights (64 keys)
  float* sks = (float*)(smem + 64512);
  short* WsS = (short*)Wsb;    // stride 72 shorts

  const int qrow0 = t0 + 32 * w;

  // Q A-frags + per-row scale factors, direct from global (read once)
  i32x4 aq[2][2];
  #pragma unroll
  for (int qt = 0; qt < 2; ++qt)
    #pragma unroll
    for (int hf = 0; hf < 2; ++hf)
      aq[qt][hf] = *(const i32x4*)(qq + ((size_t)bh * T_ + qrow0 + qt * 16 + l15) * D_ + hf * 64 + quad * 16);

  float f0[2][4];
  #pragma unroll
  for (int qt = 0; qt < 2; ++qt)
    #pragma unroll
    for (int r = 0; r < 4; ++r)
      f0[qt][r] = sq[(size_t)bh * T_ + qrow0 + qt * 16 + quad * 4 + r] * INV_SQRT_D;

  // ---- pass 1: exact rowmax of c*skc (positive f0 factored out) ----
  float rmaxc[2][4];
  #pragma unroll
  for (int qt = 0; qt < 2; ++qt)
    #pragma unroll
    for (int r = 0; r < 4; ++r) rmaxc[qt][r] = -3e38f;

  for (int s0 = 0; s0 < T_; s0 += 64) {
    __syncthreads();   // WAR vs previous chunk's K reads
    {
      const int8_t* kbase = kq + ((size_t)bh * T_ + s0) * D_;
      #pragma unroll
      for (int it = 0; it < 2; ++it) {
        int idx = tid + it * 256;
        int row = idx >> 3, seg = idx & 7;
        *(uint4*)(Ks + row * 144 + seg * 16) = *(const uint4*)(kbase + row * 128 + seg * 16);
      }
      if (tid < 64) sks[tid] = sk[(size_t)bh * T_ + s0 + tid];
    }
    __syncthreads();
    #pragma unroll
    for (int kt = 0; kt < 4; ++kt) {
      const int key = kt * 16 + l15;
      i32x4 b0 = *(const i32x4*)(Ks + key * 144 + quad * 16);
      i32x4 b1 = *(const i32x4*)(Ks + key * 144 + 64 + quad * 16);
      const float skc = sks[key];
      #pragma unroll
      for (int qt = 0; qt < 2; ++qt) {
        i32x4 c = i32x4{0, 0, 0, 0};
        c = mfma_i8(aq[qt][0], b0, c);
        c = mfma_i8(aq[qt][1], b1, c);
        #pragma unroll
        for (int r = 0; r < 4; ++r)
          rmaxc[qt][r] = fmaxf(rmaxc[qt][r], (float)c[r] * skc);
      }
    }
  }
  #pragma unroll
  for (int mm = 1; mm < 16; mm <<= 1)
    #pragma unroll
    for (int qt = 0; qt < 2; ++qt)
      #pragma unroll
      for (int r = 0; r < 4; ++r)
        rmaxc[qt][r] = fmaxf(rmaxc[qt][r], __shfl_xor(rmaxc[qt][r], mm, 64));

  float f1[2][4], g[2][4];
  #pragma unroll
  for (int qt = 0; qt < 2; ++qt)
    #pragma unroll
    for (int r = 0; r < 4; ++r) {
      f1[qt][r] = f0[qt][r] * LOG2E;
      g[qt][r]  = LOG2_127 - (rmaxc[qt][r] * f0[qt][r]) * LOG2E;
    }

  // ---- pass 2: quantized softmax + PV ----
  float zacc[2][4] = {};
  f32x4 yacc[2][8];
  #pragma unroll
  for (int qt = 0; qt < 2; ++qt)
    #pragma unroll
    for (int dt = 0; dt < 8; ++dt) yacc[qt][dt] = f32x4{0.f, 0.f, 0.f, 0.f};

  for (int s0 = 0; s0 < T_; s0 += 64) {
    __syncthreads();   // WAR: prev chunk's K/V reads complete
    {
      const int8_t* kbase = kq + ((size_t)bh * T_ + s0) * D_;
      #pragma unroll
      for (int it = 0; it < 2; ++it) {
        int idx = tid + it * 256;
        int row = idx >> 3, seg = idx & 7;
        *(uint4*)(Ks + row * 144 + seg * 16) = *(const uint4*)(kbase + row * 128 + seg * 16);
      }
      // V hi/lo: 2048 x 16B
      #pragma unroll
      for (int it = 0; it < 8; ++it) {
        int idx = tid + it * 256;
        int half = idx >> 10;
        int rem = idx & 1023;
        int d = rem >> 3, seg = rem & 7;
        const short* src = (half ? vloT : vhiT) + ((size_t)bh * D_ + d) * T_ + s0 + seg * 8;
        char* dst = (half ? Vl : Vh) + d * 144 + seg * 16;
        *(uint4*)dst = *(const uint4*)src;
      }
      if (tid < 64) sks[tid] = sk[(size_t)bh * T_ + s0 + tid];
    }
    __syncthreads();   // RAW: staging visible

    #pragma unroll
    for (int kt = 0; kt < 4; ++kt) {
      const int key = kt * 16 + l15;
      i32x4 b0 = *(const i32x4*)(Ks + key * 144 + quad * 16);
      i32x4 b1 = *(const i32x4*)(Ks + key * 144 + 64 + quad * 16);
      const float skc = sks[key];
      #pragma unroll
      for (int qt = 0; qt < 2; ++qt) {
        i32x4 c = i32x4{0, 0, 0, 0};
        c = mfma_i8(aq[qt][0], b0, c);
        c = mfma_i8(aq[qt][1], b1, c);
        #pragma unroll
        for (int r = 0; r < 4; ++r) {
          float t = (float)c[r] * skc;
          float wu = fast_exp2(fmaf(t, f1[qt][r], g[qt][r]));  // = 127*exp(s-m)
          zacc[qt][r] += wu;
          float wq = rintf(wu);                                 // integer in [0,127]
          short hb = (short)(__float_as_uint(wq) >> 16);        // exact bf16
          WsS[(32 * w + qt * 16 + quad * 4 + r) * 72 + key] = hb;
        }
      }
    }
    __threadfence_block();   // wave-private W rows: LDS drain only, no barrier
    // PV
    #pragma unroll
    for (int kc = 0; kc < 2; ++kc) {
      s16x8 a0 = *(const s16x8*)(Wsb + (32 * w + l15) * 144 + kc * 64 + quad * 16);
      s16x8 a1 = *(const s16x8*)(Wsb + (32 * w + 16 + l15) * 144 + kc * 64 + quad * 16);
      #pragma unroll
      for (int dt = 0; dt < 8; ++dt) {
        s16x8 vh = *(const s16x8*)(Vh + (dt * 16 + l15) * 144 + kc * 64 + quad * 16);
        s16x8 vl = *(const s16x8*)(Vl + (dt * 16 + l15) * 144 + kc * 64 + quad * 16);
        yacc[0][dt] = mfma_bf16(a0, vh, yacc[0][dt]);
        yacc[0][dt] = mfma_bf16(a0, vl, yacc[0][dt]);
        yacc[1][dt] = mfma_bf16(a1, vh, yacc[1][dt]);
        yacc[1][dt] = mfma_bf16(a1, vl, yacc[1][dt]);
      }
    }
  }

  #pragma unroll
  for (int mm = 1; mm < 16; mm <<= 1)
    #pragma unroll
    for (int qt = 0; qt < 2; ++qt)
      #pragma unroll
      for (int r = 0; r < 4; ++r)
        zacc[qt][r] += __shfl_xor(zacc[qt][r], mm, 64);

  // ---- epilogue: y = yacc/zacc (zacc = 127Z), per-(token,head) act_quant ----
  const int b = bh >> 4;
  const int h = bh & 15;
  #pragma unroll
  for (int qt = 0; qt < 2; ++qt)
    #pragma unroll
    for (int r = 0; r < 4; ++r) {
      float ym = 0.f;
      #pragma unroll
      for (int dt = 0; dt < 8; ++dt) ym = fmaxf(ym, fabsf(yacc[qt][dt][r]));
      #pragma unroll
      for (int mm = 1; mm < 16; mm <<= 1) ym = fmaxf(ym, __shfl_xor(ym, mm, 64));
      const float invz = 1.f / zacc[qt][r];
      const float ymt = fmaxf(ym * invz, EPSF);
      const float fs = 127.f / ymt;
      const int tglob = t0 + 32 * w + qt * 16 + quad * 4 + r;
      const size_t rowbase = ((size_t)(b * T_ + tglob)) * C_ + h * D_;
      #pragma unroll
      for (int dt = 0; dt < 8; ++dt) {
        float yv = yacc[qt][dt][r] * invz;
        float qv = fminf(fmaxf(rintf(yv * fs), -128.f), 127.f);
        yq[rowbase + dt * 16 + l15] = (int8_t)qv;
      }
      if (l15 == 0)
        sy[(size_t)(b * T_ + tglob) * H_ + h] = ymt / 127.f;
    }
}

// ---------------- output projection: i8 MFMA, LDS-staged (R2/R4-proven) --------------
// grid (C/64, R/128). Wave tile 64x32; int32 acc per head, folded every 2 K-chunks.
__global__ __launch_bounds__(256) void outproj_mfma_kernel(
    const int8_t* __restrict__ yq, const float* __restrict__ sy,
    const int8_t* __restrict__ Wt, const float* __restrict__ sw4,
    float* __restrict__ outp)
{
  const int n0  = blockIdx.x * 64;
  const int r0  = blockIdx.y * 128;
  const int tid = (int)threadIdx.x;
  const int wv   = tid >> 6;
  const int lane = tid & 63;
  const int quad = lane >> 4;
  const int l15  = lane & 15;
  const int rh   = wv >> 1, ch = wv & 1;
  const int8_t* Wm = Wt + (size_t)3 * C_ * C_;

  __shared__ __align__(16) char As[128 * 80];
  __shared__ __align__(16) char Bs[64 * 80];
  __shared__ float sYs[128][16];
  for (int idx = tid; idx < 128 * 16; idx += 256)
    sYs[idx >> 4][idx & 15] = sy[(size_t)(r0 + (idx >> 4)) * H_ + (idx & 15)];

  i32x4 iacc[4][2];
  f32x4 facc[4][2];
  #pragma unroll
  for (int i = 0; i < 4; ++i)
    #pragma unroll
    for (int j = 0; j < 2; ++j) { iacc[i][j] = i32x4{0,0,0,0}; facc[i][j] = f32x4{0.f,0.f,0.f,0.f}; }

  for (int kc = 0; kc < 32; ++kc) {
    const int k0 = kc * 64;
    #pragma unroll
    for (int it = 0; it < 2; ++it) {
      int idx = tid + it * 256;
      int row = idx >> 2, seg = idx & 3;
      *(uint4*)(As + row * 80 + seg * 16) =
          *(const uint4*)(yq + (size_t)(r0 + row) * C_ + k0 + seg * 16);
    }
    {
      int col = tid >> 2, seg = tid & 3;
      *(uint4*)(Bs + col * 80 + seg * 16) =
          *(const uint4*)(Wm + (size_t)(n0 + col) * C_ + k0 + seg * 16);
    }
    __syncthreads();
    i32x4 a[4], b[2];
    #pragma unroll
    for (int rt = 0; rt < 4; ++rt)
      a[rt] = *(const i32x4*)(As + (rh * 64 + rt * 16 + l15) * 80 + quad * 16);
    #pragma unroll
    for (int ct = 0; ct < 2; ++ct)
      b[ct] = *(const i32x4*)(Bs + (ch * 32 + ct * 16 + l15) * 80 + quad * 16);
    #pragma unroll
    for (int rt = 0; rt < 4; ++rt)
      #pragma unroll
      for (int ct = 0; ct < 2; ++ct)
        iacc[rt][ct] = mfma_i8(a[rt], b[ct], iacc[rt][ct]);
    __syncthreads();
    if (kc & 1) {
      const int hd = kc >> 1;
      #pragma unroll
      for (int rt = 0; rt < 4; ++rt)
        #pragma unroll
        for (int r = 0; r < 4; ++r) {
          const float s = sYs[rh * 64 + rt * 16 + quad * 4 + r][hd];
          #pragma unroll
          for (int ct = 0; ct < 2; ++ct)
            facc[rt][ct][r] += (float)iacc[rt][ct][r] * s;
        }
      #pragma unroll
      for (int rt = 0; rt < 4; ++rt)
        #pragma unroll
        for (int ct = 0; ct < 2; ++ct) iacc[rt][ct] = i32x4{0,0,0,0};
    }
  }
  const float swp = sw4[3];
  #pragma unroll
  for (int rt = 0; rt < 4; ++rt)
    #pragma unroll
    for (int r = 0; r < 4; ++r) {
      const int rowl = rh * 64 + rt * 16 + quad * 4 + r;
      #pragma unroll
      for (int ct = 0; ct < 2; ++ct)
        outp[(size_t)(r0 + rowl) * C_ + n0 + ch * 32 + ct * 16 + l15] =
            facc[rt][ct][r] * swp;
    }
}

// ---------------- final per-token act_quant ----------------
__global__ __launch_bounds__(256) void final_quant_kernel(
    const float* __restrict__ outp, float* __restrict__ out)
{
  const int r = blockIdx.x;
  const float* xr = outp + (size_t)r * C_;
  float am = 0.f;
  for (int j = threadIdx.x; j < C_; j += 256) am = fmaxf(am, fabsf(xr[j]));
  __shared__ float sm[256];
  sm[threadIdx.x] = am;
  __syncthreads();
  for (int o = 128; o > 0; o >>= 1) {
    if ((int)threadIdx.x < o) sm[threadIdx.x] = fmaxf(sm[threadIdx.x], sm[threadIdx.x + o]);
    __syncthreads();
  }
  const float m = fmaxf(sm[0], EPSF);
  const float scale = 127.f / m;
  const float inv = m / 127.f;
  for (int j = threadIdx.x; j < C_; j += 256) {
    float q = fminf(fmaxf(rintf(xr[j] * scale), -128.f), 127.f);
    out[(size_t)r * C_ + j] = q * inv;
  }
}

} // namespace

extern "C" void kernel_launch(void* const* d_in, const int* in_sizes, int n_in,
                              void* d_out, int out_size, void* d_ws, size_t ws_size,
                              hipStream_t stream)
{
  (void)in_sizes; (void)n_in; (void)out_size; (void)ws_size;
  const float* x  = (const float*)d_in[0];
  const float* W0 = (const float*)d_in[1];
  const float* W1 = (const float*)d_in[2];
  const float* W2 = (const float*)d_in[3];
  const float* W3 = (const float*)d_in[4];

  char* ws = (char*)d_ws;
  double* wsum = (double*)(ws + OFF_WSUM);
  float*  swv  = (float*) (ws + OFF_SW);
  int8_t* Wt   = (int8_t*)(ws + OFF_WT);
  int8_t* xq   = (int8_t*)(ws + OFF_XQ);
  float*  sx   = (float*) (ws + OFF_SX);
  int8_t* qkv  = (int8_t*)(ws + OFF_QKV);
  float*  sqkv = (float*) (ws + OFF_SQKV);
  int8_t* yqp  = (int8_t*)(ws + OFF_YQ);
  float*  syp  = (float*) (ws + OFF_SY);
  float*  outp = (float*) (ws + OFF_OUTP);
  short*  vhiT = (short*) (ws + OFF_VHI);          // aliases outp
  short*  vloT = vhiT + VT_ELEMS;

  hipMemsetAsync(d_ws, 0, 256, stream);
  hipLaunchKernelGGL(wabs_sum_kernel, dim3(256), dim3(256), 0, stream, W0, W1, W2, W3, wsum);
  hipLaunchKernelGGL(wquant_kernel, dim3(4096), dim3(256), 0, stream, W0, W1, W2, W3, wsum, Wt, swv);
  hipLaunchKernelGGL(xquant_kernel, dim3(R_), dim3(256), 0, stream, x, xq, sx);
  hipLaunchKernelGGL(proj_mfma_kernel, dim3(H_, R_ / 128, 3), dim3(256), 0, stream,
                     xq, sx, Wt, swv, qkv, sqkv);
  hipLaunchKernelGGL(vtrans_kernel, dim3(T_ / 64, B_ * H_), dim3(256), 0, stream,
                     qkv + (size_t)2 * R_ * C_, sqkv + (size_t)2 * R_ * H_, vhiT, vloT);
  hipLaunchKernelGGL(attn_mfma_kernel, dim3(B_ * H_, T_ / 128), dim3(256), 0, stream,
                     qkv, qkv + (size_t)R_ * C_,
                     sqkv, sqkv + (size_t)R_ * H_,
                     vhiT, vloT, yqp, syp);
  hipLaunchKernelGGL(outproj_mfma_kernel, dim3(C_ / 64, R_ / 128), dim3(256), 0, stream,
                     yqp, syp, Wt, swv, outp);
  hipLaunchKernelGGL(final_quant_kernel, dim3(R_), dim3(256), 0, stream, outp, (float*)d_out);
}